// Round 10
// baseline (790.509 us; speedup 1.0000x reference)
//
#include <hip/hip_runtime.h>

#define N_NODES   50000
#define N_EDGES   600000
#define IN_CH     300
#define HID       128
#define N_CLASSES 2
#define N_GRAPHS  128
#define BN_EPS    1e-5f

#define NB ((N_NODES + 511) / 512)   // scan blocks = 98
#define KP1 320

typedef __attribute__((ext_vector_type(8))) short bf8_t;   // 8 bf16 (4 VGPRs)
typedef __attribute__((ext_vector_type(4))) float f4_t;    // MFMA acc

// bf16 round-to-nearest-even helpers
__device__ __forceinline__ unsigned short f2bf(float x) {
    union { float f; unsigned u; } q; q.f = x;
    unsigned r = q.u + 0x7fffu + ((q.u >> 16) & 1u);
    return (unsigned short)(r >> 16);
}
__device__ __forceinline__ float bf2f(unsigned short h) {
    union { float f; unsigned u; } q; q.u = ((unsigned)h) << 16; return q.f;
}

// async global->LDS 16B copy: LDS dest = wave-uniform base + lane*16
__device__ __forceinline__ void async_cp16(const void* g, void* l) {
    __builtin_amdgcn_global_load_lds(
        (const __attribute__((address_space(1))) unsigned int*)g,
        (__attribute__((address_space(3))) unsigned int*)l, 16, 0, 0);
}

// ---------------------------------------------------------------------------
// degree count
// ---------------------------------------------------------------------------
__global__ __launch_bounds__(256) void deg_kernel(const int* __restrict__ dst,
                                                  int* __restrict__ ideg) {
    int e = blockIdx.x * 256 + threadIdx.x;
    if (e < N_EDGES) atomicAdd(&ideg[dst[e]], 1);
}

// ---------------------------------------------------------------------------
// 3-phase exclusive scan of ideg -> row_start (+ invdeg fused in phase 3)
// ---------------------------------------------------------------------------
__global__ __launch_bounds__(256) void scan_p1(const int* __restrict__ ideg,
                                               int* __restrict__ bsum) {
    int b = blockIdx.x, t = threadIdx.x;
    int i0 = b * 512 + t * 2;
    int s = 0;
    if (i0 < N_NODES) {
        int2 v = *(const int2*)&ideg[i0];
        s = v.x + v.y;
    }
#pragma unroll
    for (int d = 1; d < 64; d <<= 1) s += __shfl_down(s, d);
    __shared__ int ws[4];
    int lane = t & 63, wv = t >> 6;
    if (lane == 0) ws[wv] = s;
    __syncthreads();
    if (t == 0) bsum[b] = ws[0] + ws[1] + ws[2] + ws[3];
}

__global__ __launch_bounds__(128) void scan_p2(int* __restrict__ bsum,
                                               int* __restrict__ row_start) {
    __shared__ int sh[128];
    int t = threadIdx.x;
    int v = (t < NB) ? bsum[t] : 0;
    sh[t] = v;
    __syncthreads();
#pragma unroll
    for (int off = 1; off < 128; off <<= 1) {
        int u = (t >= off) ? sh[t - off] : 0;
        __syncthreads();
        sh[t] += u;
        __syncthreads();
    }
    if (t < NB) bsum[t] = sh[t] - v;          // exclusive
    if (t == NB - 1) row_start[N_NODES] = sh[t];
}

__global__ __launch_bounds__(256) void scan_p3(const int* __restrict__ ideg,
                                               const int* __restrict__ bsum,
                                               int* __restrict__ row_start,
                                               float* __restrict__ invdeg) {
    int b = blockIdx.x, t = threadIdx.x;
    int lane = t & 63, wv = t >> 6;
    int i0 = b * 512 + t * 2;
    int v0 = 0, v1 = 0;
    if (i0 < N_NODES) {
        int2 v = *(const int2*)&ideg[i0];
        v0 = v.x; v1 = v.y;
    }
    int tot = v0 + v1;
    int s = tot;
#pragma unroll
    for (int d = 1; d < 64; d <<= 1) {
        int u = __shfl_up(s, d);
        if (lane >= d) s += u;
    }
    __shared__ int ws[4];
    if (lane == 63) ws[wv] = s;
    __syncthreads();
    int woff = 0;
    for (int w = 0; w < wv; ++w) woff += ws[w];
    int base = bsum[b] + woff + (s - tot);
    if (i0 < N_NODES) {
        row_start[i0]     = base;
        row_start[i0 + 1] = base + v0;
        invdeg[i0]     = 1.0f / fmaxf((float)v0, 1.0f);
        invdeg[i0 + 1] = 1.0f / fmaxf((float)v1, 1.0f);
    }
}

__global__ __launch_bounds__(256) void fill_kernel(const int* __restrict__ src,
                                                   const int* __restrict__ dst,
                                                   const int* __restrict__ row_start,
                                                   int* __restrict__ cursor,
                                                   int* __restrict__ csr_src) {
    int e = blockIdx.x * 256 + threadIdx.x;
    if (e >= N_EDGES) return;
    int d = dst[e];
    int pos = row_start[d] + atomicAdd(&cursor[d], 1);
    csr_src[pos] = src[e];
}

// ---------------------------------------------------------------------------
// x -> split bf16 hi/lo planes (M x 320, zero-padded cols 300..319)
// ---------------------------------------------------------------------------
__global__ __launch_bounds__(256) void prep_x(const float* __restrict__ x,
                                              unsigned short* __restrict__ Ahi,
                                              unsigned short* __restrict__ Alo) {
    int idx = blockIdx.x * 256 + threadIdx.x;  // over N_NODES * 80
    if (idx >= N_NODES * (KP1 / 4)) return;
    int row = idx / (KP1 / 4);
    int c4  = (idx - row * (KP1 / 4)) * 4;
    float4 v = make_float4(0.f, 0.f, 0.f, 0.f);
    if (c4 < IN_CH) v = *(const float4*)&x[(long)row * IN_CH + c4];
    ushort4 h, l;
    h.x = f2bf(v.x); l.x = f2bf(v.x - bf2f(h.x));
    h.y = f2bf(v.y); l.y = f2bf(v.y - bf2f(h.y));
    h.z = f2bf(v.z); l.z = f2bf(v.z - bf2f(h.z));
    h.w = f2bf(v.w); l.w = f2bf(v.w - bf2f(h.w));
    *(ushort4*)&Ahi[(long)row * KP1 + c4] = h;
    *(ushort4*)&Alo[(long)row * KP1 + c4] = l;
}

// ---------------------------------------------------------------------------
// weight prep for ALL layers: BT[n][k] (256 x Kp, bf16 hi/lo, zero-pad k>=K)
// ---------------------------------------------------------------------------
__global__ __launch_bounds__(256) void prep_w_all(const float* __restrict__ W1l,
                                                  const float* __restrict__ W1r,
                                                  const float* __restrict__ W2l,
                                                  const float* __restrict__ W2r,
                                                  const float* __restrict__ W3l,
                                                  const float* __restrict__ W3r,
                                                  unsigned short* __restrict__ B1h,
                                                  unsigned short* __restrict__ B1l,
                                                  unsigned short* __restrict__ B2h,
                                                  unsigned short* __restrict__ B2l,
                                                  unsigned short* __restrict__ B3h,
                                                  unsigned short* __restrict__ B3l) {
    int layer = blockIdx.y;
    int Kp = (layer == 0) ? KP1 : HID;
    int K  = (layer == 0) ? IN_CH : HID;
    const float* Wl = (layer == 0) ? W1l : ((layer == 1) ? W2l : W3l);
    const float* Wr = (layer == 0) ? W1r : ((layer == 1) ? W2r : W3r);
    unsigned short* Bh = (layer == 0) ? B1h : ((layer == 1) ? B2h : B3h);
    unsigned short* Bl = (layer == 0) ? B1l : ((layer == 1) ? B2l : B3l);
    int idx = blockIdx.x * 256 + threadIdx.x;
    if (idx >= 256 * Kp) return;
    int n = idx / Kp;
    int k = idx - n * Kp;
    float v = 0.f;
    if (k < K) v = (n < 128) ? Wl[k * 128 + n] : Wr[k * 128 + (n - 128)];
    unsigned short h = f2bf(v);
    unsigned short l = f2bf(v - bf2f(h));
    Bh[idx] = h;
    Bl[idx] = l;
}

// ---------------------------------------------------------------------------
// split-bf16 MFMA GEMM, persistent-B / barrier-free K-loop:
//   C0 = A@Wl , C1 = A@Wr + bias   (N = 128+128)
// 512 threads = 8 waves; block tile 128(M) x 256(N); wave = 64x64 (4x4 MFMA).
// B: 128-wide K-chunk held in 128 KB dynamic LDS (hi+lo), staged per chunk
//    with 2 barriers; inner K-steps have NO barriers (A global->VGPR ping-pong).
// LDS chunk-XOR swizzle (16B chunk cp = clog ^ (row&7)) -> conflict-free reads;
// applied on the staging side by permuting each lane's global source chunk.
// ---------------------------------------------------------------------------
__global__ __launch_bounds__(512, 2) void gemm_mfma(const unsigned short* __restrict__ Ahi,
                                                    const unsigned short* __restrict__ Alo,
                                                    int M, int Kp,
                                                    const unsigned short* __restrict__ Bhi,
                                                    const unsigned short* __restrict__ Blo,
                                                    const float* __restrict__ bias,
                                                    float* __restrict__ C0,
                                                    float* __restrict__ C1) {
    extern __shared__ __align__(16) unsigned short sB[];   // 2 x 256 x 128 ushorts
    unsigned short* sBh = sB;
    unsigned short* sBl = sB + 256 * 128;

    const int tid  = threadIdx.x;
    const int lane = tid & 63;
    const int wave = tid >> 6;      // 0..7
    const int wq   = wave >> 2;     // row half 0/1
    const int wn   = wave & 3;      // N 64-slice
    const int l16  = lane & 15;
    const int quad = lane >> 4;
    const long m0  = (long)blockIdx.x * 128;
    const int  n0  = wn * 64;

    f4_t acc[4][4];
#pragma unroll
    for (int mt = 0; mt < 4; ++mt)
#pragma unroll
        for (int nt = 0; nt < 4; ++nt) acc[mt][nt] = (f4_t){0.f, 0.f, 0.f, 0.f};

    // A fragment pointers: row m0 + wq*64 + mt*16 + l16, col quad*8
    const unsigned short* gA[4][2];
#pragma unroll
    for (int mt = 0; mt < 4; ++mt) {
        long r = m0 + wq * 64 + mt * 16 + l16;
        if (r >= M) r = M - 1;                 // clamp: garbage rows never stored
        gA[mt][0] = Ahi + r * Kp + quad * 8;
        gA[mt][1] = Alo + r * Kp + quad * 8;
    }

    // B staging: 8 insts/plane/chunk; inst j covers rows j*32 + wave*4 + (lane>>4).
    // lane writes physical 16B-chunk (lane&15) of its row; to realize the XOR
    // swizzle it FETCHES global chunk cg = (lane&15) ^ (row&7).
    const int srow = wave * 4 + (lane >> 4);            // row within 32-row group
    const int cg   = (lane & 15) ^ (srow & 7);          // global 16B-chunk index
    const unsigned short* gBh_base = Bhi + (long)srow * Kp + cg * 8;
    const unsigned short* gBl_base = Blo + (long)srow * Kp + cg * 8;
    const int ldsbase = (wave * 4) * 128;               // + j*32*128, + lane*16B by HW

    const int tot_steps = Kp >> 5;                      // 10 or 4

    // fragment-read swizzle: physical chunk = (s*4 + quad) ^ (l16&7)
    auto computeStep = [&](bf8_t (&a)[4][2], int s) {
#pragma unroll
        for (int nt = 0; nt < 4; ++nt) {
            int row = n0 + nt * 16 + l16;
            int cp  = ((s * 4 + quad) ^ (l16 & 7)) * 8;
            bf8_t bh = *(const bf8_t*)&sBh[row * 128 + cp];
            bf8_t bl = *(const bf8_t*)&sBl[row * 128 + cp];
#pragma unroll
            for (int mt = 0; mt < 4; ++mt) {
                acc[mt][nt] = __builtin_amdgcn_mfma_f32_16x16x32_bf16(a[mt][0], bh, acc[mt][nt], 0, 0, 0);
                acc[mt][nt] = __builtin_amdgcn_mfma_f32_16x16x32_bf16(a[mt][1], bh, acc[mt][nt], 0, 0, 0);
                acc[mt][nt] = __builtin_amdgcn_mfma_f32_16x16x32_bf16(a[mt][0], bl, acc[mt][nt], 0, 0, 0);
            }
        }
    };
    auto loadA = [&](bf8_t (&a)[4][2], int koff) {
#pragma unroll
        for (int mt = 0; mt < 4; ++mt) {
            a[mt][0] = *(const bf8_t*)(gA[mt][0] + koff);
            a[mt][1] = *(const bf8_t*)(gA[mt][1] + koff);
        }
    };

    bf8_t aP[2][4][2];
    loadA(aP[0], 0);                                    // prefetch A(0)
    int gs = 0;                                         // global K-step

    for (int kc = 0; kc < Kp; kc += 128) {
        const int ks = min(128, Kp - kc) >> 5;          // inner steps: 4,4,2 / 4
        __syncthreads();                                // prev chunk compute done
#pragma unroll
        for (int j = 0; j < 8; ++j) {
            async_cp16(gBh_base + (long)j * 32 * Kp + kc, &sBh[ldsbase + j * 32 * 128]);
            async_cp16(gBl_base + (long)j * 32 * Kp + kc, &sBl[ldsbase + j * 32 * 128]);
        }
        __syncthreads();                                // drain B chunk
        for (int s = 0; s < ks; ++s, ++gs) {
            const int cur = gs & 1;
            if (gs + 1 < tot_steps) loadA(aP[cur ^ 1], (gs + 1) * 32);
            computeStep(aP[cur], s);                    // no barrier
        }
    }

    // epilogue: wave-uniform half selection (n0<128 -> C0, else C1 + bias)
    const bool left = (wn < 2);
    float* __restrict__ Cb = left ? C0 : C1;
    float badd[4];
    int   ncol[4];
#pragma unroll
    for (int nt = 0; nt < 4; ++nt) {
        int ng = n0 + nt * 16 + l16;
        ncol[nt] = left ? ng : (ng - 128);
        badd[nt] = left ? 0.f : bias[ng - 128];
    }
#pragma unroll
    for (int mt = 0; mt < 4; ++mt) {
#pragma unroll
        for (int r = 0; r < 4; ++r) {
            long row = m0 + wq * 64 + mt * 16 + quad * 4 + r;
            if (row < M) {
#pragma unroll
                for (int nt = 0; nt < 4; ++nt)
                    Cb[row * 128 + ncol[nt]] = acc[mt][nt][r] + badd[nt];
            }
        }
    }
}

// ---------------------------------------------------------------------------
// CSR gather: out[n] += invdeg[n] * sum_{j in adj(n)} Pl[csr_src[j]]
// 32 lanes/node (float4/lane), 8 nodes/block, 8+4 edge unroll for MLP.
// ---------------------------------------------------------------------------
__global__ __launch_bounds__(256) void gather_agg(const float* __restrict__ Pl,
                                                  const int* __restrict__ row_start,
                                                  const int* __restrict__ csr_src,
                                                  const float* __restrict__ invdeg,
                                                  float* __restrict__ out) {
    int slot = threadIdx.x >> 5;
    int lane = threadIdx.x & 31;
    int node = blockIdx.x * 8 + slot;
    if (node >= N_NODES) return;
    int beg = row_start[node];
    int end = row_start[node + 1];
    const float* base = Pl + lane * 4;
    float sx = 0.f, sy = 0.f, sz = 0.f, sw = 0.f;
    int j = beg;
    for (; j + 8 <= end; j += 8) {
        int idx[8];
#pragma unroll
        for (int u = 0; u < 8; ++u) idx[u] = csr_src[j + u];
        float4 v[8];
#pragma unroll
        for (int u = 0; u < 8; ++u) v[u] = *(const float4*)(base + (long)idx[u] * HID);
#pragma unroll
        for (int u = 0; u < 8; ++u) {
            sx += v[u].x; sy += v[u].y; sz += v[u].z; sw += v[u].w;
        }
    }
    if (j + 4 <= end) {
        int idx[4];
#pragma unroll
        for (int u = 0; u < 4; ++u) idx[u] = csr_src[j + u];
        float4 v[4];
#pragma unroll
        for (int u = 0; u < 4; ++u) v[u] = *(const float4*)(base + (long)idx[u] * HID);
#pragma unroll
        for (int u = 0; u < 4; ++u) {
            sx += v[u].x; sy += v[u].y; sz += v[u].z; sw += v[u].w;
        }
        j += 4;
    }
    for (; j < end; ++j) {
        int i0 = csr_src[j];
        float4 v0 = *(const float4*)(base + (long)i0 * HID);
        sx += v0.x; sy += v0.y; sz += v0.z; sw += v0.w;
    }
    float w = invdeg[node];
    float* o = out + (long)node * HID + lane * 4;
    float4 cur = *(float4*)o;
    cur.x += sx * w;
    cur.y += sy * w;
    cur.z += sz * w;
    cur.w += sw * w;
    *(float4*)o = cur;
}

// ---------------------------------------------------------------------------
// BatchNorm: stats -> apply(+ReLU, finalize fused)
// ---------------------------------------------------------------------------
__global__ __launch_bounds__(256) void bn_stats(const float* __restrict__ h,
                                                float* __restrict__ sums) {
    int c    = threadIdx.x & 127;
    int half = threadIdx.x >> 7;
    float s = 0.f, s2 = 0.f;
    for (int r = blockIdx.x * 2 + half; r < N_NODES; r += gridDim.x * 2) {
        float v = h[(long)r * HID + c];
        s  += v;
        s2 += v * v;
    }
    atomicAdd(&sums[c], s);
    atomicAdd(&sums[HID + c], s2);
}

__global__ __launch_bounds__(256) void bn_apply_relu(float* __restrict__ h,
                                                     const float* __restrict__ sums,
                                                     const float* __restrict__ gamma,
                                                     const float* __restrict__ beta,
                                                     unsigned short* __restrict__ Hhi,
                                                     unsigned short* __restrict__ Hlo) {
    long i = (long)blockIdx.x * 256 + threadIdx.x;
    if (i >= (long)N_NODES * 32) return;
    int c4 = (int)(i & 31) * 4;
    const float invn = 1.0f / (float)N_NODES;
    float4 s  = *(const float4*)&sums[c4];
    float4 s2 = *(const float4*)&sums[HID + c4];
    float4 g  = *(const float4*)&gamma[c4];
    float4 be = *(const float4*)&beta[c4];
    float4 sc, sh;
    {
        float mu, var;
        mu = s.x * invn; var = s2.x * invn - mu * mu; sc.x = g.x * rsqrtf(var + BN_EPS); sh.x = be.x - mu * sc.x;
        mu = s.y * invn; var = s2.y * invn - mu * mu; sc.y = g.y * rsqrtf(var + BN_EPS); sh.y = be.y - mu * sc.y;
        mu = s.z * invn; var = s2.z * invn - mu * mu; sc.z = g.z * rsqrtf(var + BN_EPS); sh.z = be.z - mu * sc.z;
        mu = s.w * invn; var = s2.w * invn - mu * mu; sc.w = g.w * rsqrtf(var + BN_EPS); sh.w = be.w - mu * sc.w;
    }
    float4 v = *(float4*)&h[i * 4];
    v.x = fmaxf(v.x * sc.x + sh.x, 0.f);
    v.y = fmaxf(v.y * sc.y + sh.y, 0.f);
    v.z = fmaxf(v.z * sc.z + sh.z, 0.f);
    v.w = fmaxf(v.w * sc.w + sh.w, 0.f);
    if (Hhi) {
        ushort4 hh, ll;
        hh.x = f2bf(v.x); ll.x = f2bf(v.x - bf2f(hh.x));
        hh.y = f2bf(v.y); ll.y = f2bf(v.y - bf2f(hh.y));
        hh.z = f2bf(v.z); ll.z = f2bf(v.z - bf2f(hh.z));
        hh.w = f2bf(v.w); ll.w = f2bf(v.w - bf2f(hh.w));
        *(ushort4*)&Hhi[i * 4] = hh;
        *(ushort4*)&Hlo[i * 4] = ll;
    } else {
        *(float4*)&h[i * 4] = v;
    }
}

// ---------------------------------------------------------------------------
// global mean pool
// ---------------------------------------------------------------------------
#define POOL_ROWS 128
__global__ __launch_bounds__(128) void pool_kernel(const float* __restrict__ h,
                                                   const int* __restrict__ batch,
                                                   float* __restrict__ pooled,
                                                   float* __restrict__ cnt) {
    int c  = threadIdx.x;
    int r0 = blockIdx.x * POOL_ROWS;
    if (r0 >= N_NODES) return;
    int r1 = min(r0 + POOL_ROWS, N_NODES);
    int cur = batch[r0];
    float acc = 0.f, n = 0.f;
    for (int r = r0; r < r1; ++r) {
        int b = batch[r];
        if (b != cur) {
            atomicAdd(&pooled[cur * HID + c], acc);
            if (c == 0) atomicAdd(&cnt[cur], n);
            acc = 0.f;
            n   = 0.f;
            cur = b;
        }
        acc += h[(long)r * HID + c];
        n   += 1.f;
    }
    atomicAdd(&pooled[cur * HID + c], acc);
    if (c == 0) atomicAdd(&cnt[cur], n);
}

// ---------------------------------------------------------------------------
// head
// ---------------------------------------------------------------------------
__global__ __launch_bounds__(128) void head_kernel(const float* __restrict__ pooled,
                                                   const float* __restrict__ cnt,
                                                   const float* __restrict__ Wc,
                                                   const float* __restrict__ bc,
                                                   float* __restrict__ out) {
    int g = threadIdx.x;
    float inv = 1.0f / fmaxf(cnt[g], 1.0f);
    float o0 = bc[0], o1 = bc[1];
    for (int c = 0; c < HID; ++c) {
        float v = pooled[g * HID + c] * inv;
        out[N_GRAPHS * N_CLASSES + g * HID + c] = v;
        o0 += v * Wc[c * 2 + 0];
        o1 += v * Wc[c * 2 + 1];
    }
    out[g * 2 + 0] = o0;
    out[g * 2 + 1] = o1;
}

// ---------------------------------------------------------------------------
// launch
// ---------------------------------------------------------------------------
extern "C" void kernel_launch(void* const* d_in, const int* in_sizes, int n_in,
                              void* d_out, int out_size, void* d_ws, size_t ws_size,
                              hipStream_t stream) {
    const float* x     = (const float*)d_in[0];
    const int*   ei    = (const int*)d_in[1];
    const int*   batch = (const int*)d_in[2];
    const float* W1l = (const float*)d_in[3];
    const float* W1r = (const float*)d_in[4];
    const float* b1  = (const float*)d_in[5];
    const float* g1  = (const float*)d_in[6];
    const float* be1 = (const float*)d_in[7];
    const float* W2l = (const float*)d_in[8];
    const float* W2r = (const float*)d_in[9];
    const float* b2  = (const float*)d_in[10];
    const float* g2  = (const float*)d_in[11];
    const float* be2 = (const float*)d_in[12];
    const float* W3l = (const float*)d_in[13];
    const float* W3r = (const float*)d_in[14];
    const float* b3  = (const float*)d_in[15];
    const float* g3  = (const float*)d_in[16];
    const float* be3 = (const float*)d_in[17];
    const float* Wc  = (const float*)d_in[18];
    const float* bc  = (const float*)d_in[19];

    const int* src = ei;
    const int* dst = ei + N_EDGES;

    float* ws = (float*)d_ws;
    const long FEAT = (long)N_NODES * HID;
    float* buf0 = ws;
    float* buf1 = ws + FEAT;
    float* buf2 = ws + 2 * FEAT;
    int*   ideg      = (int*)(ws + 3 * FEAT);        // 50000
    int*   cursor    = ideg + N_NODES;               // 50000 (adjacent: 1 memset)
    int*   row_start = cursor + N_NODES;             // 50001 (pad to 50004)
    int*   csr_src   = row_start + N_NODES + 4;      // 600000
    int*   bsum      = csr_src + N_EDGES;            // 128
    float* invdeg    = (float*)(bsum + 128);         // 50000
    float* sums      = invdeg + N_NODES;             // 3*256 (+pooled+cnt: 1 memset)
    float* pooled    = sums + 3 * 2 * HID;           // 16384
    float* cnt       = pooled + N_GRAPHS * HID;      // 128
    unsigned short* B1h  = (unsigned short*)(cnt + N_GRAPHS);  // 256*320
    unsigned short* B1l  = B1h + 256 * KP1;
    unsigned short* B2h  = B1l + 256 * KP1;                    // 256*128
    unsigned short* B2l  = B2h + 256 * HID;
    unsigned short* B3h  = B2l + 256 * HID;
    unsigned short* B3l  = B3h + 256 * HID;
    unsigned short* Axhi = B3l + 256 * HID;                    // 50000*320
    unsigned short* Axlo = Axhi + (long)N_NODES * KP1;
    unsigned short* Hhi  = Axlo + (long)N_NODES * KP1;         // 50000*128
    unsigned short* Hlo  = Hhi + FEAT;

    float* outp = (float*)d_out;

    const int LDS_B = 2 * 256 * 128 * (int)sizeof(unsigned short);  // 131072
    static int attr_done = 0;
    // host-side, idempotent, not a stream op (graph-capture safe)
    hipFuncSetAttribute((const void*)gemm_mfma,
                        hipFuncAttributeMaxDynamicSharedMemorySize, LDS_B);

    const int gemm_grid   = (N_NODES + 127) / 128;   // 391
    const int gather_grid = (N_NODES + 7) / 8;       // 6250
    const int apply_grid  = (int)(((long)N_NODES * 32 + 255) / 256);
    const int pool_grid   = (N_NODES + POOL_ROWS - 1) / POOL_ROWS;
    const int prepx_grid  = (N_NODES * (KP1 / 4) + 255) / 256;
    const dim3 prepw_grid((256 * KP1 + 255) / 256, 3);

    // --- zero scratch (2 merged memsets) ---
    hipMemsetAsync(ideg, 0, 2 * N_NODES * sizeof(int), stream);
    hipMemsetAsync(sums, 0,
                   (3 * 2 * HID + N_GRAPHS * HID + N_GRAPHS) * sizeof(float), stream);

    // --- CSR build ---
    deg_kernel<<<(N_EDGES + 255) / 256, 256, 0, stream>>>(dst, ideg);
    scan_p1<<<NB, 256, 0, stream>>>(ideg, bsum);
    scan_p2<<<1, 128, 0, stream>>>(bsum, row_start);
    scan_p3<<<NB, 256, 0, stream>>>(ideg, bsum, row_start, invdeg);
    fill_kernel<<<(N_EDGES + 255) / 256, 256, 0, stream>>>(src, dst, row_start, cursor, csr_src);

    // --- operand prep ---
    prep_x<<<prepx_grid, 256, 0, stream>>>(x, Axhi, Axlo);
    prep_w_all<<<prepw_grid, 256, 0, stream>>>(W1l, W1r, W2l, W2r, W3l, W3r,
                                               B1h, B1l, B2h, B2l, B3h, B3l);

    // ---------------- layer 1 (A=x split, Kp=320) ----------------
    gemm_mfma<<<gemm_grid, 512, LDS_B, stream>>>(Axhi, Axlo, N_NODES, KP1, B1h, B1l, b1, buf0, buf1);
    gather_agg<<<gather_grid, 256, 0, stream>>>(buf0, row_start, csr_src, invdeg, buf1);
    bn_stats<<<256, 256, 0, stream>>>(buf1, sums);
    bn_apply_relu<<<apply_grid, 256, 0, stream>>>(buf1, sums, g1, be1, Hhi, Hlo);

    // ---------------- layer 2 (A=h1 split, Kp=128) ----------------
    gemm_mfma<<<gemm_grid, 512, LDS_B, stream>>>(Hhi, Hlo, N_NODES, HID, B2h, B2l, b2, buf0, buf2);
    gather_agg<<<gather_grid, 256, 0, stream>>>(buf0, row_start, csr_src, invdeg, buf2);
    bn_stats<<<256, 256, 0, stream>>>(buf2, sums + 256);
    bn_apply_relu<<<apply_grid, 256, 0, stream>>>(buf2, sums + 256, g2, be2, Hhi, Hlo);

    // ---------------- layer 3 (A=h2 split, Kp=128) ----------------
    gemm_mfma<<<gemm_grid, 512, LDS_B, stream>>>(Hhi, Hlo, N_NODES, HID, B3h, B3l, b3, buf0, buf1);
    gather_agg<<<gather_grid, 256, 0, stream>>>(buf0, row_start, csr_src, invdeg, buf1);
    bn_stats<<<256, 256, 0, stream>>>(buf1, sums + 512);
    bn_apply_relu<<<apply_grid, 256, 0, stream>>>(buf1, sums + 512, g3, be3, nullptr, nullptr);

    // ---------------- pool + head ----------------
    pool_kernel<<<pool_grid, 128, 0, stream>>>(buf1, batch, pooled, cnt);
    head_kernel<<<1, 128, 0, stream>>>(pooled, cnt, Wc, bc, outp);
}

// Round 11
// 544.285 us; speedup vs baseline: 1.4524x; 1.4524x over previous
//
#include <hip/hip_runtime.h>

#define N_NODES   50000
#define N_EDGES   600000
#define IN_CH     300
#define HID       128
#define N_CLASSES 2
#define N_GRAPHS  128
#define BN_EPS    1e-5f

#define NB ((N_NODES + 511) / 512)   // scan blocks = 98
#define KP1 320
#define NREP 32                      // replicated BN-stat accumulators

typedef __attribute__((ext_vector_type(8))) short bf8_t;   // 8 bf16 (4 VGPRs)
typedef __attribute__((ext_vector_type(4))) float f4_t;    // MFMA acc

// bf16 round-to-nearest-even helpers
__device__ __forceinline__ unsigned short f2bf(float x) {
    union { float f; unsigned u; } q; q.f = x;
    unsigned r = q.u + 0x7fffu + ((q.u >> 16) & 1u);
    return (unsigned short)(r >> 16);
}
__device__ __forceinline__ float bf2f(unsigned short h) {
    union { float f; unsigned u; } q; q.u = ((unsigned)h) << 16; return q.f;
}

// async global->LDS 16B copy: LDS dest = wave-uniform base + lane*16
__device__ __forceinline__ void async_cp16(const void* g, void* l) {
    __builtin_amdgcn_global_load_lds(
        (const __attribute__((address_space(1))) unsigned int*)g,
        (__attribute__((address_space(3))) unsigned int*)l, 16, 0, 0);
}

// ---------------------------------------------------------------------------
// degree count
// ---------------------------------------------------------------------------
__global__ __launch_bounds__(256) void deg_kernel(const int* __restrict__ dst,
                                                  int* __restrict__ ideg) {
    int e = blockIdx.x * 256 + threadIdx.x;
    if (e < N_EDGES) atomicAdd(&ideg[dst[e]], 1);
}

// ---------------------------------------------------------------------------
// single-dispatch exclusive scan (decoupled lookback) + invdeg
// bsum/bflag zeroed by host memset each call (ws is poisoned otherwise).
// Publish happens BEFORE any spin -> no deadlock; 98 blocks all co-resident.
// Cross-XCD visibility via device-scope atomics + threadfence.
// ---------------------------------------------------------------------------
__global__ __launch_bounds__(256) void scan_fused(const int* __restrict__ ideg,
                                                  int* __restrict__ row_start,
                                                  float* __restrict__ invdeg,
                                                  int* __restrict__ bsum,
                                                  int* __restrict__ bflag) {
    int b = blockIdx.x, t = threadIdx.x;
    int lane = t & 63, wv = t >> 6;
    int i0 = b * 512 + t * 2;
    int v0 = 0, v1 = 0;
    if (i0 < N_NODES) {
        int2 v = *(const int2*)&ideg[i0];
        v0 = v.x; v1 = v.y;
    }
    int tot = v0 + v1;
    int s = tot;                              // inclusive wave scan
#pragma unroll
    for (int d = 1; d < 64; d <<= 1) {
        int u = __shfl_up(s, d);
        if (lane >= d) s += u;
    }
    __shared__ int ws[4];
    if (lane == 63) ws[wv] = s;
    __syncthreads();
    int btot = ws[0] + ws[1] + ws[2] + ws[3];
    if (t == 0) {                             // publish early
        atomicExch(&bsum[b], btot);
        __threadfence();
        atomicExch(&bflag[b], 1);
    }
    // parallel lookback: thread i (<b) collects predecessor i
    int part = 0;
    if (t < b) {
        while (atomicAdd(&bflag[t], 0) == 0) {}
        part = atomicAdd(&bsum[t], 0);
    }
#pragma unroll
    for (int d = 1; d < 64; d <<= 1) part += __shfl_down(part, d);
    __shared__ int ps[4];
    if (lane == 0) ps[wv] = part;
    __syncthreads();
    int boff = ps[0] + ps[1] + ps[2] + ps[3];
    int woff = 0;
    for (int w = 0; w < wv; ++w) woff += ws[w];
    int base = boff + woff + (s - tot);       // exclusive prefix for i0
    if (i0 < N_NODES) {
        row_start[i0]     = base;
        row_start[i0 + 1] = base + v0;
        invdeg[i0]     = 1.0f / fmaxf((float)v0, 1.0f);
        invdeg[i0 + 1] = 1.0f / fmaxf((float)v1, 1.0f);
    }
    if (t == 0 && b == NB - 1) row_start[N_NODES] = boff + btot;
}

__global__ __launch_bounds__(256) void fill_kernel(const int* __restrict__ src,
                                                   const int* __restrict__ dst,
                                                   const int* __restrict__ row_start,
                                                   int* __restrict__ cursor,
                                                   int* __restrict__ csr_src) {
    int e = blockIdx.x * 256 + threadIdx.x;
    if (e >= N_EDGES) return;
    int d = dst[e];
    int pos = row_start[d] + atomicAdd(&cursor[d], 1);
    csr_src[pos] = src[e];
}

// ---------------------------------------------------------------------------
// weight prep for ALL layers: BT[n][k] (256 x Kp, bf16 hi/lo, zero-pad k>=K)
// ---------------------------------------------------------------------------
__global__ __launch_bounds__(256) void prep_w_all(const float* __restrict__ W1l,
                                                  const float* __restrict__ W1r,
                                                  const float* __restrict__ W2l,
                                                  const float* __restrict__ W2r,
                                                  const float* __restrict__ W3l,
                                                  const float* __restrict__ W3r,
                                                  unsigned short* __restrict__ B1h,
                                                  unsigned short* __restrict__ B1l,
                                                  unsigned short* __restrict__ B2h,
                                                  unsigned short* __restrict__ B2l,
                                                  unsigned short* __restrict__ B3h,
                                                  unsigned short* __restrict__ B3l) {
    int layer = blockIdx.y;
    int Kp = (layer == 0) ? KP1 : HID;
    int K  = (layer == 0) ? IN_CH : HID;
    const float* Wl = (layer == 0) ? W1l : ((layer == 1) ? W2l : W3l);
    const float* Wr = (layer == 0) ? W1r : ((layer == 1) ? W2r : W3r);
    unsigned short* Bh = (layer == 0) ? B1h : ((layer == 1) ? B2h : B3h);
    unsigned short* Bl = (layer == 0) ? B1l : ((layer == 1) ? B2l : B3l);
    int idx = blockIdx.x * 256 + threadIdx.x;
    if (idx >= 256 * Kp) return;
    int n = idx / Kp;
    int k = idx - n * Kp;
    float v = 0.f;
    if (k < K) v = (n < 128) ? Wl[k * 128 + n] : Wr[k * 128 + (n - 128)];
    unsigned short h = f2bf(v);
    unsigned short l = f2bf(v - bf2f(h));
    Bh[idx] = h;
    Bl[idx] = l;
}

// ---------------------------------------------------------------------------
// split-bf16 MFMA GEMM (R6 structure + XOR bank swizzle):
//   C0 = A@Wl , C1 = A@Wr + bias   (N = 128+128)
// block 64(M) x 256(N), 4 waves, wave 64x64 = 4x4 MFMA 16x16x32; single-buffer
// A(8KB)+B(32KB) LDS via cp16, 2 barriers/step.
// Swizzle invariant: LDS slot (row, cp) holds global chunk cp ^ ((row>>1)&3).
// stage source chunk cg = (lane&3) ^ ((lane>>3)&3); read chunk = quad ^ ((l16>>1)&3).
// ---------------------------------------------------------------------------
__global__ __launch_bounds__(256) void gemm_mfma(const unsigned short* __restrict__ Ahi,
                                                 const unsigned short* __restrict__ Alo,
                                                 int M, int Kp,
                                                 const unsigned short* __restrict__ Bhi,
                                                 const unsigned short* __restrict__ Blo,
                                                 const float* __restrict__ bias,
                                                 float* __restrict__ C0,
                                                 float* __restrict__ C1) {
    __shared__ __align__(16) unsigned short sAh[64 * 32];
    __shared__ __align__(16) unsigned short sAl[64 * 32];
    __shared__ __align__(16) unsigned short sBh[256 * 32];
    __shared__ __align__(16) unsigned short sBl[256 * 32];

    const int tid  = threadIdx.x;
    const int lane = tid & 63;
    const int wave = tid >> 6;
    const int l16  = lane & 15;
    const int quad = lane >> 4;
    const long m0  = (long)blockIdx.x * 64;
    const int  n0  = wave * 64;

    f4_t acc[4][4];
#pragma unroll
    for (int mt = 0; mt < 4; ++mt)
#pragma unroll
        for (int nt = 0; nt < 4; ++nt) acc[mt][nt] = (f4_t){0.f, 0.f, 0.f, 0.f};

    const int cg = ((lane & 3) ^ ((lane >> 3) & 3)) * 8;   // swizzled source col
    long asr = m0 + wave * 16 + (lane >> 2);
    if (asr >= M) asr = M - 1;  // clamp: garbage rows never stored
    const unsigned short* gAh = Ahi + asr * Kp + cg;
    const unsigned short* gAl = Alo + asr * Kp + cg;
    unsigned short* lAh = &sAh[wave * 512];
    unsigned short* lAl = &sAl[wave * 512];
    const unsigned short* gBh[4];
    const unsigned short* gBl[4];
    unsigned short* lBh[4];
    unsigned short* lBl[4];
#pragma unroll
    for (int j = 0; j < 4; ++j) {
        long br = wave * 64 + j * 16 + (lane >> 2);
        gBh[j] = Bhi + br * Kp + cg;
        gBl[j] = Blo + br * Kp + cg;
        lBh[j] = &sBh[wave * 2048 + j * 512];
        lBl[j] = &sBl[wave * 2048 + j * 512];
    }
    const int rsw = (quad ^ ((l16 >> 1) & 3)) * 8;         // swizzled read chunk

    for (int k0 = 0; k0 < Kp; k0 += 32) {
        async_cp16(gAh + k0, lAh);
        async_cp16(gAl + k0, lAl);
#pragma unroll
        for (int j = 0; j < 4; ++j) {
            async_cp16(gBh[j] + k0, lBh[j]);
            async_cp16(gBl[j] + k0, lBl[j]);
        }
        __syncthreads();

        bf8_t ah[4], al[4];
#pragma unroll
        for (int mt = 0; mt < 4; ++mt) {
            ah[mt] = *(const bf8_t*)&sAh[(mt * 16 + l16) * 32 + rsw];
            al[mt] = *(const bf8_t*)&sAl[(mt * 16 + l16) * 32 + rsw];
        }
#pragma unroll
        for (int nt = 0; nt < 4; ++nt) {
            bf8_t bh = *(const bf8_t*)&sBh[(n0 + nt * 16 + l16) * 32 + rsw];
            bf8_t bl = *(const bf8_t*)&sBl[(n0 + nt * 16 + l16) * 32 + rsw];
#pragma unroll
            for (int mt = 0; mt < 4; ++mt) {
                acc[mt][nt] = __builtin_amdgcn_mfma_f32_16x16x32_bf16(ah[mt], bh, acc[mt][nt], 0, 0, 0);
                acc[mt][nt] = __builtin_amdgcn_mfma_f32_16x16x32_bf16(al[mt], bh, acc[mt][nt], 0, 0, 0);
                acc[mt][nt] = __builtin_amdgcn_mfma_f32_16x16x32_bf16(ah[mt], bl, acc[mt][nt], 0, 0, 0);
            }
        }
        __syncthreads();
    }

    const bool left = (n0 < 128);
    float* __restrict__ Cb = left ? C0 : C1;
    float badd[4];
    int   ncol[4];
#pragma unroll
    for (int nt = 0; nt < 4; ++nt) {
        int ng = n0 + nt * 16 + l16;
        ncol[nt] = left ? ng : (ng - 128);
        badd[nt] = left ? 0.f : bias[ng - 128];
    }
#pragma unroll
    for (int mt = 0; mt < 4; ++mt) {
#pragma unroll
        for (int r = 0; r < 4; ++r) {
            long row = m0 + mt * 16 + quad * 4 + r;
            if (row < M) {
#pragma unroll
                for (int nt = 0; nt < 4; ++nt)
                    Cb[row * 128 + ncol[nt]] = acc[mt][nt][r] + badd[nt];
            }
        }
    }
}

// ---------------------------------------------------------------------------
// layer-1 GEMM: A = x (fp32, stride 300), split in-kernel (once per block).
// Thread t stages row t>>2, logical chunk t&3 (8 floats, guarded vs K=300),
// splits to bf16 hi/lo, ds_write_b128 to swizzled physical chunk.
// B staged via cp16 as above (Kp=320, zero-padded).
// ---------------------------------------------------------------------------
__global__ __launch_bounds__(256) void gemm_mfma_x(const float* __restrict__ X,
                                                   int M,
                                                   const unsigned short* __restrict__ Bhi,
                                                   const unsigned short* __restrict__ Blo,
                                                   const float* __restrict__ bias,
                                                   float* __restrict__ C0,
                                                   float* __restrict__ C1) {
    __shared__ __align__(16) unsigned short sAh[64 * 32];
    __shared__ __align__(16) unsigned short sAl[64 * 32];
    __shared__ __align__(16) unsigned short sBh[256 * 32];
    __shared__ __align__(16) unsigned short sBl[256 * 32];

    const int tid  = threadIdx.x;
    const int lane = tid & 63;
    const int wave = tid >> 6;
    const int l16  = lane & 15;
    const int quad = lane >> 4;
    const long m0  = (long)blockIdx.x * 64;
    const int  n0  = wave * 64;

    f4_t acc[4][4];
#pragma unroll
    for (int mt = 0; mt < 4; ++mt)
#pragma unroll
        for (int nt = 0; nt < 4; ++nt) acc[mt][nt] = (f4_t){0.f, 0.f, 0.f, 0.f};

    // A split-staging: thread t -> local row ar = t>>2, logical chunk cl = t&3
    const int ar  = tid >> 2;
    const int cl  = tid & 3;
    const int cpa = cl ^ ((ar >> 1) & 3);      // physical chunk (swizzle)
    long agr = m0 + ar;
    if (agr >= M) agr = M - 1;                 // clamp: garbage rows never stored
    const float* gX = X + agr * IN_CH;

    // B staging (cp16, swizzled source)
    const int cg = ((lane & 3) ^ ((lane >> 3) & 3)) * 8;
    const unsigned short* gBh[4];
    const unsigned short* gBl[4];
    unsigned short* lBh[4];
    unsigned short* lBl[4];
#pragma unroll
    for (int j = 0; j < 4; ++j) {
        long br = wave * 64 + j * 16 + (lane >> 2);
        gBh[j] = Bhi + br * KP1 + cg;
        gBl[j] = Blo + br * KP1 + cg;
        lBh[j] = &sBh[wave * 2048 + j * 512];
        lBl[j] = &sBl[wave * 2048 + j * 512];
    }
    const int rsw = (quad ^ ((l16 >> 1) & 3)) * 8;

    for (int k0 = 0; k0 < KP1; k0 += 32) {
#pragma unroll
        for (int j = 0; j < 4; ++j) {
            async_cp16(gBh[j] + k0, lBh[j]);
            async_cp16(gBl[j] + k0, lBl[j]);
        }
        // A: load 8 fp32 (guarded), split, write 2 x b128 (float4 blocks align with 300)
        float f[8];
        const int gk = k0 + cl * 8;
#pragma unroll
        for (int hh = 0; hh < 2; ++hh) {
            int g4 = gk + hh * 4;
            float4 v = (g4 + 4 <= IN_CH) ? *(const float4*)(gX + g4)
                                         : make_float4(0.f, 0.f, 0.f, 0.f);
            f[hh * 4 + 0] = v.x; f[hh * 4 + 1] = v.y;
            f[hh * 4 + 2] = v.z; f[hh * 4 + 3] = v.w;
        }
        bf8_t h8, l8;
#pragma unroll
        for (int j = 0; j < 8; ++j) {
            unsigned short h = f2bf(f[j]);
            h8[j] = (short)h;
            l8[j] = (short)f2bf(f[j] - bf2f(h));
        }
        *(bf8_t*)&sAh[ar * 32 + cpa * 8] = h8;
        *(bf8_t*)&sAl[ar * 32 + cpa * 8] = l8;
        __syncthreads();

        bf8_t ah[4], al[4];
#pragma unroll
        for (int mt = 0; mt < 4; ++mt) {
            ah[mt] = *(const bf8_t*)&sAh[(mt * 16 + l16) * 32 + rsw];
            al[mt] = *(const bf8_t*)&sAl[(mt * 16 + l16) * 32 + rsw];
        }
#pragma unroll
        for (int nt = 0; nt < 4; ++nt) {
            bf8_t bh = *(const bf8_t*)&sBh[(n0 + nt * 16 + l16) * 32 + rsw];
            bf8_t bl = *(const bf8_t*)&sBl[(n0 + nt * 16 + l16) * 32 + rsw];
#pragma unroll
            for (int mt = 0; mt < 4; ++mt) {
                acc[mt][nt] = __builtin_amdgcn_mfma_f32_16x16x32_bf16(ah[mt], bh, acc[mt][nt], 0, 0, 0);
                acc[mt][nt] = __builtin_amdgcn_mfma_f32_16x16x32_bf16(al[mt], bh, acc[mt][nt], 0, 0, 0);
                acc[mt][nt] = __builtin_amdgcn_mfma_f32_16x16x32_bf16(ah[mt], bl, acc[mt][nt], 0, 0, 0);
            }
        }
        __syncthreads();
    }

    const bool left = (n0 < 128);
    float* __restrict__ Cb = left ? C0 : C1;
    float badd[4];
    int   ncol[4];
#pragma unroll
    for (int nt = 0; nt < 4; ++nt) {
        int ng = n0 + nt * 16 + l16;
        ncol[nt] = left ? ng : (ng - 128);
        badd[nt] = left ? 0.f : bias[ng - 128];
    }
#pragma unroll
    for (int mt = 0; mt < 4; ++mt) {
#pragma unroll
        for (int r = 0; r < 4; ++r) {
            long row = m0 + mt * 16 + quad * 4 + r;
            if (row < M) {
#pragma unroll
                for (int nt = 0; nt < 4; ++nt)
                    Cb[row * 128 + ncol[nt]] = acc[mt][nt][r] + badd[nt];
            }
        }
    }
}

// ---------------------------------------------------------------------------
// CSR gather + BN-stat tail: out[n] += invdeg[n]*sum(Pl[adj]); per-channel
// sum/sumsq LDS-reduced, one atomicAdd per channel into rep[blockIdx&31].
// 32 lanes/node, 8 nodes/block (R7 TLP), 8+4 edge unroll.
// ---------------------------------------------------------------------------
__global__ __launch_bounds__(256) void gather_agg(const float* __restrict__ Pl,
                                                  const int* __restrict__ row_start,
                                                  const int* __restrict__ csr_src,
                                                  const float* __restrict__ invdeg,
                                                  float* __restrict__ out,
                                                  float* __restrict__ rep) {
    int slot = threadIdx.x >> 5;
    int lane = threadIdx.x & 31;
    int node = blockIdx.x * 8 + slot;          // grid exact: 6250*8 = 50000
    int beg = row_start[node];
    int end = row_start[node + 1];
    const float* base = Pl + lane * 4;
    float sx = 0.f, sy = 0.f, sz = 0.f, sw = 0.f;
    int j = beg;
    for (; j + 8 <= end; j += 8) {
        int idx[8];
#pragma unroll
        for (int u = 0; u < 8; ++u) idx[u] = csr_src[j + u];
        float4 v[8];
#pragma unroll
        for (int u = 0; u < 8; ++u) v[u] = *(const float4*)(base + (long)idx[u] * HID);
#pragma unroll
        for (int u = 0; u < 8; ++u) {
            sx += v[u].x; sy += v[u].y; sz += v[u].z; sw += v[u].w;
        }
    }
    if (j + 4 <= end) {
        int idx[4];
#pragma unroll
        for (int u = 0; u < 4; ++u) idx[u] = csr_src[j + u];
        float4 v[4];
#pragma unroll
        for (int u = 0; u < 4; ++u) v[u] = *(const float4*)(base + (long)idx[u] * HID);
#pragma unroll
        for (int u = 0; u < 4; ++u) {
            sx += v[u].x; sy += v[u].y; sz += v[u].z; sw += v[u].w;
        }
        j += 4;
    }
    for (; j < end; ++j) {
        int i0 = csr_src[j];
        float4 v0 = *(const float4*)(base + (long)i0 * HID);
        sx += v0.x; sy += v0.y; sz += v0.z; sw += v0.w;
    }
    float w = invdeg[node];
    float* o = out + (long)node * HID + lane * 4;
    float4 cur = *(float4*)o;
    cur.x += sx * w;
    cur.y += sy * w;
    cur.z += sz * w;
    cur.w += sw * w;
    *(float4*)o = cur;

    // ---- BN stats tail: reduce 8 slots -> 256 atomics into rep slice ----
    __shared__ float red[8][HID];
    float* repb = rep + (blockIdx.x & (NREP - 1)) * 256;
    *(float4*)&red[slot][lane * 4] = make_float4(cur.x, cur.y, cur.z, cur.w);
    __syncthreads();
    if (threadIdx.x < HID) {
        float tsum = 0.f;
#pragma unroll
        for (int s = 0; s < 8; ++s) tsum += red[s][threadIdx.x];
        atomicAdd(&repb[threadIdx.x], tsum);
    }
    __syncthreads();
    *(float4*)&red[slot][lane * 4] = make_float4(cur.x * cur.x, cur.y * cur.y,
                                                 cur.z * cur.z, cur.w * cur.w);
    __syncthreads();
    if (threadIdx.x < HID) {
        float tsum = 0.f;
#pragma unroll
        for (int s = 0; s < 8; ++s) tsum += red[s][threadIdx.x];
        atomicAdd(&repb[HID + threadIdx.x], tsum);
    }
}

// ---------------------------------------------------------------------------
// BN apply(+ReLU): preamble reduces NREP replicated stat slices -> scale/shift
// in LDS; body as before. Hhi!=null -> write bf16 hi/lo; else fp32 in place.
// ---------------------------------------------------------------------------
__global__ __launch_bounds__(256) void bn_apply_relu(float* __restrict__ h,
                                                     const float* __restrict__ rep,
                                                     const float* __restrict__ gamma,
                                                     const float* __restrict__ beta,
                                                     unsigned short* __restrict__ Hhi,
                                                     unsigned short* __restrict__ Hlo) {
    __shared__ float S[256];    // [sum(128) | sumsq(128)]
    __shared__ float SC[256];   // [scale(128) | shift(128)]
    int t = threadIdx.x;
    float a = 0.f;
#pragma unroll
    for (int r = 0; r < NREP; ++r) a += rep[r * 256 + t];
    S[t] = a;
    __syncthreads();
    if (t < HID) {
        const float invn = 1.0f / (float)N_NODES;
        float mu  = S[t] * invn;
        float var = S[HID + t] * invn - mu * mu;
        float sc  = gamma[t] * rsqrtf(var + BN_EPS);
        SC[t]       = sc;
        SC[HID + t] = beta[t] - mu * sc;
    }
    __syncthreads();

    long i = (long)blockIdx.x * 256 + t;
    if (i >= (long)N_NODES * 32) return;
    int c4 = (int)(i & 31) * 4;
    float4 sc = *(const float4*)&SC[c4];
    float4 sh = *(const float4*)&SC[HID + c4];
    float4 v  = *(float4*)&h[i * 4];
    v.x = fmaxf(v.x * sc.x + sh.x, 0.f);
    v.y = fmaxf(v.y * sc.y + sh.y, 0.f);
    v.z = fmaxf(v.z * sc.z + sh.z, 0.f);
    v.w = fmaxf(v.w * sc.w + sh.w, 0.f);
    if (Hhi) {
        ushort4 hh, ll;
        hh.x = f2bf(v.x); ll.x = f2bf(v.x - bf2f(hh.x));
        hh.y = f2bf(v.y); ll.y = f2bf(v.y - bf2f(hh.y));
        hh.z = f2bf(v.z); ll.z = f2bf(v.z - bf2f(hh.z));
        hh.w = f2bf(v.w); ll.w = f2bf(v.w - bf2f(hh.w));
        *(ushort4*)&Hhi[i * 4] = hh;
        *(ushort4*)&Hlo[i * 4] = ll;
    } else {
        *(float4*)&h[i * 4] = v;
    }
}

// ---------------------------------------------------------------------------
// fused mean-pool + head: one block per graph; binary-search node range in
// sorted batch; 256 thr = 2 row-halves x 128 channels; head via LDS reduce.
// out = [logits(128x2) | hg(128x128)]
// ---------------------------------------------------------------------------
__global__ __launch_bounds__(256) void poolhead_kernel(const float* __restrict__ h,
                                                       const int* __restrict__ batch,
                                                       const float* __restrict__ Wc,
                                                       const float* __restrict__ bc,
                                                       float* __restrict__ out) {
    int g = blockIdx.x;
    int t = threadIdx.x;
    int c = t & 127;
    int half = t >> 7;
    __shared__ int lo_sh, hi_sh;
    if (t == 0) {
        int lo = 0, hi = N_NODES;
        while (lo < hi) { int m = (lo + hi) >> 1; if (batch[m] < g) lo = m + 1; else hi = m; }
        lo_sh = lo;
        int lo2 = lo, hi2 = N_NODES;
        while (lo2 < hi2) { int m = (lo2 + hi2) >> 1; if (batch[m] < g + 1) lo2 = m + 1; else hi2 = m; }
        hi_sh = lo2;
    }
    __syncthreads();
    int lo = lo_sh, hi = hi_sh;
    float acc = 0.f;
    for (int r = lo + half; r < hi; r += 2) acc += h[(long)r * HID + c];
    __shared__ float red[2][HID];
    red[half][c] = acc;
    __syncthreads();
    __shared__ float r0[HID], r1[HID];
    if (t < HID) {
        float inv = 1.0f / fmaxf((float)(hi - lo), 1.0f);
        float v = (red[0][t] + red[1][t]) * inv;
        out[N_GRAPHS * N_CLASSES + g * HID + t] = v;   // hg
        r0[t] = v * Wc[t * 2 + 0];
        r1[t] = v * Wc[t * 2 + 1];
    }
    __syncthreads();
    if (t < 2) {
        const float* rr = t ? r1 : r0;
        float sum = bc[t];
        for (int i = 0; i < HID; ++i) sum += rr[i];
        out[g * 2 + t] = sum;
    }
}

// ---------------------------------------------------------------------------
// launch
// ---------------------------------------------------------------------------
extern "C" void kernel_launch(void* const* d_in, const int* in_sizes, int n_in,
                              void* d_out, int out_size, void* d_ws, size_t ws_size,
                              hipStream_t stream) {
    const float* x     = (const float*)d_in[0];
    const int*   ei    = (const int*)d_in[1];
    const int*   batch = (const int*)d_in[2];
    const float* W1l = (const float*)d_in[3];
    const float* W1r = (const float*)d_in[4];
    const float* b1  = (const float*)d_in[5];
    const float* g1  = (const float*)d_in[6];
    const float* be1 = (const float*)d_in[7];
    const float* W2l = (const float*)d_in[8];
    const float* W2r = (const float*)d_in[9];
    const float* b2  = (const float*)d_in[10];
    const float* g2  = (const float*)d_in[11];
    const float* be2 = (const float*)d_in[12];
    const float* W3l = (const float*)d_in[13];
    const float* W3r = (const float*)d_in[14];
    const float* b3  = (const float*)d_in[15];
    const float* g3  = (const float*)d_in[16];
    const float* be3 = (const float*)d_in[17];
    const float* Wc  = (const float*)d_in[18];
    const float* bc  = (const float*)d_in[19];

    const int* src = ei;
    const int* dst = ei + N_EDGES;

    float* ws = (float*)d_ws;
    const long FEAT = (long)N_NODES * HID;
    float* buf0 = ws;
    float* buf1 = ws + FEAT;
    float* buf2 = ws + 2 * FEAT;
    // memset1 region: ideg + cursor + bsum + bflag  (contiguous ints)
    int*   ideg      = (int*)(ws + 3 * FEAT);        // 50000
    int*   cursor    = ideg + N_NODES;               // 50000
    int*   bsum      = cursor + N_NODES;             // 128
    int*   bflag     = bsum + 128;                   // 128
    int*   row_start = bflag + 128;                  // 50001 (pad 50004)
    int*   csr_src   = row_start + N_NODES + 4;      // 600000
    float* invdeg    = (float*)(csr_src + N_EDGES);  // 50000
    // memset2 region: reps (3 layers x NREP x 256 floats)
    float* reps      = invdeg + N_NODES;             // 3*32*256 = 24576
    unsigned short* B1h = (unsigned short*)(reps + 3 * NREP * 256);  // 256*320
    unsigned short* B1l = B1h + 256 * KP1;
    unsigned short* B2h = B1l + 256 * KP1;                           // 256*128
    unsigned short* B2l = B2h + 256 * HID;
    unsigned short* B3h = B2l + 256 * HID;
    unsigned short* B3l = B3h + 256 * HID;
    unsigned short* Hhi = B3l + 256 * HID;                           // 50000*128
    unsigned short* Hlo = Hhi + FEAT;

    float* outp = (float*)d_out;

    const int gemm_grid   = (N_NODES + 63) / 64;     // 782
    const int gather_grid = N_NODES / 8;             // 6250 exact
    const int apply_grid  = (int)(((long)N_NODES * 32 + 255) / 256);
    const dim3 prepw_grid((256 * KP1 + 255) / 256, 3);

    // --- zero scratch (2 memsets; ws is poisoned 0xAA before every launch) ---
    hipMemsetAsync(ideg, 0, (2 * N_NODES + 256) * sizeof(int), stream);
    hipMemsetAsync(reps, 0, 3 * NREP * 256 * sizeof(float), stream);

    // --- CSR build (4 dispatches) ---
    deg_kernel<<<(N_EDGES + 255) / 256, 256, 0, stream>>>(dst, ideg);
    scan_fused<<<NB, 256, 0, stream>>>(ideg, row_start, invdeg, bsum, bflag);
    fill_kernel<<<(N_EDGES + 255) / 256, 256, 0, stream>>>(src, dst, row_start, cursor, csr_src);

    // --- weight prep ---
    prep_w_all<<<prepw_grid, 256, 0, stream>>>(W1l, W1r, W2l, W2r, W3l, W3r,
                                               B1h, B1l, B2h, B2l, B3h, B3l);

    // ---------------- layer 1 (A = x fp32, split in-kernel) ----------------
    gemm_mfma_x<<<gemm_grid, 256, 0, stream>>>(x, N_NODES, B1h, B1l, b1, buf0, buf1);
    gather_agg<<<gather_grid, 256, 0, stream>>>(buf0, row_start, csr_src, invdeg, buf1, reps);
    bn_apply_relu<<<apply_grid, 256, 0, stream>>>(buf1, reps, g1, be1, Hhi, Hlo);

    // ---------------- layer 2 (A = h1 split, Kp=128) ----------------
    gemm_mfma<<<gemm_grid, 256, 0, stream>>>(Hhi, Hlo, N_NODES, HID, B2h, B2l, b2, buf0, buf2);
    gather_agg<<<gather_grid, 256, 0, stream>>>(buf0, row_start, csr_src, invdeg, buf2, reps + NREP * 256);
    bn_apply_relu<<<apply_grid, 256, 0, stream>>>(buf2, reps + NREP * 256, g2, be2, Hhi, Hlo);

    // ---------------- layer 3 (A = h2 split, Kp=128) ----------------
    gemm_mfma<<<gemm_grid, 256, 0, stream>>>(Hhi, Hlo, N_NODES, HID, B3h, B3l, b3, buf0, buf1);
    gather_agg<<<gather_grid, 256, 0, stream>>>(buf0, row_start, csr_src, invdeg, buf1, reps + 2 * NREP * 256);
    bn_apply_relu<<<apply_grid, 256, 0, stream>>>(buf1, reps + 2 * NREP * 256, g3, be3, nullptr, nullptr);

    // ---------------- fused pool + head ----------------
    poolhead_kernel<<<N_GRAPHS, 256, 0, stream>>>(buf1, batch, Wc, bc, outp);
}

// Round 12
// 443.628 us; speedup vs baseline: 1.7819x; 1.2269x over previous
//
#include <hip/hip_runtime.h>

#define N_NODES   50000
#define N_EDGES   600000
#define IN_CH     300
#define HID       128
#define N_CLASSES 2
#define N_GRAPHS  128
#define BN_EPS    1e-5f

#define NB ((N_NODES + 511) / 512)   // scan blocks = 98
#define KP1 320
#define NREP 32                      // replicated BN-stat accumulators

typedef __attribute__((ext_vector_type(8))) short bf8_t;   // 8 bf16 (4 VGPRs)
typedef __attribute__((ext_vector_type(4))) float f4_t;    // MFMA acc

// bf16 round-to-nearest-even helpers
__device__ __forceinline__ unsigned short f2bf(float x) {
    union { float f; unsigned u; } q; q.f = x;
    unsigned r = q.u + 0x7fffu + ((q.u >> 16) & 1u);
    return (unsigned short)(r >> 16);
}
__device__ __forceinline__ float bf2f(unsigned short h) {
    union { float f; unsigned u; } q; q.u = ((unsigned)h) << 16; return q.f;
}

// async global->LDS 16B copy: LDS dest = wave-uniform base + lane*16
__device__ __forceinline__ void async_cp16(const void* g, void* l) {
    __builtin_amdgcn_global_load_lds(
        (const __attribute__((address_space(1))) unsigned int*)g,
        (__attribute__((address_space(3))) unsigned int*)l, 16, 0, 0);
}

// ---------------------------------------------------------------------------
// degree count
// ---------------------------------------------------------------------------
__global__ __launch_bounds__(256) void deg_kernel(const int* __restrict__ dst,
                                                  int* __restrict__ ideg) {
    int e = blockIdx.x * 256 + threadIdx.x;
    if (e < N_EDGES) atomicAdd(&ideg[dst[e]], 1);
}

// ---------------------------------------------------------------------------
// single-dispatch exclusive scan (decoupled lookback) + invdeg
// ---------------------------------------------------------------------------
__global__ __launch_bounds__(256) void scan_fused(const int* __restrict__ ideg,
                                                  int* __restrict__ row_start,
                                                  float* __restrict__ invdeg,
                                                  int* __restrict__ bsum,
                                                  int* __restrict__ bflag) {
    int b = blockIdx.x, t = threadIdx.x;
    int lane = t & 63, wv = t >> 6;
    int i0 = b * 512 + t * 2;
    int v0 = 0, v1 = 0;
    if (i0 < N_NODES) {
        int2 v = *(const int2*)&ideg[i0];
        v0 = v.x; v1 = v.y;
    }
    int tot = v0 + v1;
    int s = tot;                              // inclusive wave scan
#pragma unroll
    for (int d = 1; d < 64; d <<= 1) {
        int u = __shfl_up(s, d);
        if (lane >= d) s += u;
    }
    __shared__ int ws[4];
    if (lane == 63) ws[wv] = s;
    __syncthreads();
    int btot = ws[0] + ws[1] + ws[2] + ws[3];
    if (t == 0) {                             // publish early
        atomicExch(&bsum[b], btot);
        __threadfence();
        atomicExch(&bflag[b], 1);
    }
    int part = 0;
    if (t < b) {
        while (atomicAdd(&bflag[t], 0) == 0) {}
        part = atomicAdd(&bsum[t], 0);
    }
#pragma unroll
    for (int d = 1; d < 64; d <<= 1) part += __shfl_down(part, d);
    __shared__ int ps[4];
    if (lane == 0) ps[wv] = part;
    __syncthreads();
    int boff = ps[0] + ps[1] + ps[2] + ps[3];
    int woff = 0;
    for (int w = 0; w < wv; ++w) woff += ws[w];
    int base = boff + woff + (s - tot);       // exclusive prefix for i0
    if (i0 < N_NODES) {
        row_start[i0]     = base;
        row_start[i0 + 1] = base + v0;
        invdeg[i0]     = 1.0f / fmaxf((float)v0, 1.0f);
        invdeg[i0 + 1] = 1.0f / fmaxf((float)v1, 1.0f);
    }
    if (t == 0 && b == NB - 1) row_start[N_NODES] = boff + btot;
}

__global__ __launch_bounds__(256) void fill_kernel(const int* __restrict__ src,
                                                   const int* __restrict__ dst,
                                                   const int* __restrict__ row_start,
                                                   int* __restrict__ cursor,
                                                   int* __restrict__ csr_src) {
    int e = blockIdx.x * 256 + threadIdx.x;
    if (e >= N_EDGES) return;
    int d = dst[e];
    int pos = row_start[d] + atomicAdd(&cursor[d], 1);
    csr_src[pos] = src[e];
}

// ---------------------------------------------------------------------------
// weight prep for ALL layers: BT[n][k] (256 x Kp, bf16 hi/lo, zero-pad k>=K)
// ---------------------------------------------------------------------------
__global__ __launch_bounds__(256) void prep_w_all(const float* __restrict__ W1l,
                                                  const float* __restrict__ W1r,
                                                  const float* __restrict__ W2l,
                                                  const float* __restrict__ W2r,
                                                  const float* __restrict__ W3l,
                                                  const float* __restrict__ W3r,
                                                  unsigned short* __restrict__ B1h,
                                                  unsigned short* __restrict__ B1l,
                                                  unsigned short* __restrict__ B2h,
                                                  unsigned short* __restrict__ B2l,
                                                  unsigned short* __restrict__ B3h,
                                                  unsigned short* __restrict__ B3l) {
    int layer = blockIdx.y;
    int Kp = (layer == 0) ? KP1 : HID;
    int K  = (layer == 0) ? IN_CH : HID;
    const float* Wl = (layer == 0) ? W1l : ((layer == 1) ? W2l : W3l);
    const float* Wr = (layer == 0) ? W1r : ((layer == 1) ? W2r : W3r);
    unsigned short* Bh = (layer == 0) ? B1h : ((layer == 1) ? B2h : B3h);
    unsigned short* Bl = (layer == 0) ? B1l : ((layer == 1) ? B2l : B3l);
    int idx = blockIdx.x * 256 + threadIdx.x;
    if (idx >= 256 * Kp) return;
    int n = idx / Kp;
    int k = idx - n * Kp;
    float v = 0.f;
    if (k < K) v = (n < 128) ? Wl[k * 128 + n] : Wr[k * 128 + (n - 128)];
    unsigned short h = f2bf(v);
    unsigned short l = f2bf(v - bf2f(h));
    Bh[idx] = h;
    Bl[idx] = l;
}

// ---------------------------------------------------------------------------
// split-bf16 MFMA GEMM (R6 structure + XOR bank swizzle):
//   C0(bf16) = A@Wl , C1(fp32) = A@Wr + bias
// ---------------------------------------------------------------------------
__global__ __launch_bounds__(256) void gemm_mfma(const unsigned short* __restrict__ Ahi,
                                                 const unsigned short* __restrict__ Alo,
                                                 int M, int Kp,
                                                 const unsigned short* __restrict__ Bhi,
                                                 const unsigned short* __restrict__ Blo,
                                                 const float* __restrict__ bias,
                                                 unsigned short* __restrict__ C0,
                                                 float* __restrict__ C1) {
    __shared__ __align__(16) unsigned short sAh[64 * 32];
    __shared__ __align__(16) unsigned short sAl[64 * 32];
    __shared__ __align__(16) unsigned short sBh[256 * 32];
    __shared__ __align__(16) unsigned short sBl[256 * 32];

    const int tid  = threadIdx.x;
    const int lane = tid & 63;
    const int wave = tid >> 6;
    const int l16  = lane & 15;
    const int quad = lane >> 4;
    const long m0  = (long)blockIdx.x * 64;
    const int  n0  = wave * 64;

    f4_t acc[4][4];
#pragma unroll
    for (int mt = 0; mt < 4; ++mt)
#pragma unroll
        for (int nt = 0; nt < 4; ++nt) acc[mt][nt] = (f4_t){0.f, 0.f, 0.f, 0.f};

    const int cg = ((lane & 3) ^ ((lane >> 3) & 3)) * 8;   // swizzled source col
    long asr = m0 + wave * 16 + (lane >> 2);
    if (asr >= M) asr = M - 1;
    const unsigned short* gAh = Ahi + asr * Kp + cg;
    const unsigned short* gAl = Alo + asr * Kp + cg;
    unsigned short* lAh = &sAh[wave * 512];
    unsigned short* lAl = &sAl[wave * 512];
    const unsigned short* gBh[4];
    const unsigned short* gBl[4];
    unsigned short* lBh[4];
    unsigned short* lBl[4];
#pragma unroll
    for (int j = 0; j < 4; ++j) {
        long br = wave * 64 + j * 16 + (lane >> 2);
        gBh[j] = Bhi + br * Kp + cg;
        gBl[j] = Blo + br * Kp + cg;
        lBh[j] = &sBh[wave * 2048 + j * 512];
        lBl[j] = &sBl[wave * 2048 + j * 512];
    }
    const int rsw = (quad ^ ((l16 >> 1) & 3)) * 8;         // swizzled read chunk

    for (int k0 = 0; k0 < Kp; k0 += 32) {
        async_cp16(gAh + k0, lAh);
        async_cp16(gAl + k0, lAl);
#pragma unroll
        for (int j = 0; j < 4; ++j) {
            async_cp16(gBh[j] + k0, lBh[j]);
            async_cp16(gBl[j] + k0, lBl[j]);
        }
        __syncthreads();

        bf8_t ah[4], al[4];
#pragma unroll
        for (int mt = 0; mt < 4; ++mt) {
            ah[mt] = *(const bf8_t*)&sAh[(mt * 16 + l16) * 32 + rsw];
            al[mt] = *(const bf8_t*)&sAl[(mt * 16 + l16) * 32 + rsw];
        }
#pragma unroll
        for (int nt = 0; nt < 4; ++nt) {
            bf8_t bh = *(const bf8_t*)&sBh[(n0 + nt * 16 + l16) * 32 + rsw];
            bf8_t bl = *(const bf8_t*)&sBl[(n0 + nt * 16 + l16) * 32 + rsw];
#pragma unroll
            for (int mt = 0; mt < 4; ++mt) {
                acc[mt][nt] = __builtin_amdgcn_mfma_f32_16x16x32_bf16(ah[mt], bh, acc[mt][nt], 0, 0, 0);
                acc[mt][nt] = __builtin_amdgcn_mfma_f32_16x16x32_bf16(al[mt], bh, acc[mt][nt], 0, 0, 0);
                acc[mt][nt] = __builtin_amdgcn_mfma_f32_16x16x32_bf16(ah[mt], bl, acc[mt][nt], 0, 0, 0);
            }
        }
        __syncthreads();
    }

    const bool left = (n0 < 128);
    if (left) {
        int ncol[4];
#pragma unroll
        for (int nt = 0; nt < 4; ++nt) ncol[nt] = n0 + nt * 16 + l16;
#pragma unroll
        for (int mt = 0; mt < 4; ++mt)
#pragma unroll
            for (int r = 0; r < 4; ++r) {
                long row = m0 + mt * 16 + quad * 4 + r;
                if (row < M) {
#pragma unroll
                    for (int nt = 0; nt < 4; ++nt)
                        C0[row * 128 + ncol[nt]] = f2bf(acc[mt][nt][r]);
                }
            }
    } else {
        float badd[4];
        int   ncol[4];
#pragma unroll
        for (int nt = 0; nt < 4; ++nt) {
            int ng = n0 + nt * 16 + l16 - 128;
            ncol[nt] = ng;
            badd[nt] = bias[ng];
        }
#pragma unroll
        for (int mt = 0; mt < 4; ++mt)
#pragma unroll
            for (int r = 0; r < 4; ++r) {
                long row = m0 + mt * 16 + quad * 4 + r;
                if (row < M) {
#pragma unroll
                    for (int nt = 0; nt < 4; ++nt)
                        C1[row * 128 + ncol[nt]] = acc[mt][nt][r] + badd[nt];
                }
            }
    }
}

// ---------------------------------------------------------------------------
// layer-1 GEMM: A = x (fp32, stride 300), split in-kernel.
// ---------------------------------------------------------------------------
__global__ __launch_bounds__(256) void gemm_mfma_x(const float* __restrict__ X,
                                                   int M,
                                                   const unsigned short* __restrict__ Bhi,
                                                   const unsigned short* __restrict__ Blo,
                                                   const float* __restrict__ bias,
                                                   unsigned short* __restrict__ C0,
                                                   float* __restrict__ C1) {
    __shared__ __align__(16) unsigned short sAh[64 * 32];
    __shared__ __align__(16) unsigned short sAl[64 * 32];
    __shared__ __align__(16) unsigned short sBh[256 * 32];
    __shared__ __align__(16) unsigned short sBl[256 * 32];

    const int tid  = threadIdx.x;
    const int lane = tid & 63;
    const int wave = tid >> 6;
    const int l16  = lane & 15;
    const int quad = lane >> 4;
    const long m0  = (long)blockIdx.x * 64;
    const int  n0  = wave * 64;

    f4_t acc[4][4];
#pragma unroll
    for (int mt = 0; mt < 4; ++mt)
#pragma unroll
        for (int nt = 0; nt < 4; ++nt) acc[mt][nt] = (f4_t){0.f, 0.f, 0.f, 0.f};

    const int ar  = tid >> 2;
    const int cl  = tid & 3;
    const int cpa = cl ^ ((ar >> 1) & 3);      // physical chunk (swizzle)
    long agr = m0 + ar;
    if (agr >= M) agr = M - 1;
    const float* gX = X + agr * IN_CH;

    const int cg = ((lane & 3) ^ ((lane >> 3) & 3)) * 8;
    const unsigned short* gBh[4];
    const unsigned short* gBl[4];
    unsigned short* lBh[4];
    unsigned short* lBl[4];
#pragma unroll
    for (int j = 0; j < 4; ++j) {
        long br = wave * 64 + j * 16 + (lane >> 2);
        gBh[j] = Bhi + br * KP1 + cg;
        gBl[j] = Blo + br * KP1 + cg;
        lBh[j] = &sBh[wave * 2048 + j * 512];
        lBl[j] = &sBl[wave * 2048 + j * 512];
    }
    const int rsw = (quad ^ ((l16 >> 1) & 3)) * 8;

    for (int k0 = 0; k0 < KP1; k0 += 32) {
#pragma unroll
        for (int j = 0; j < 4; ++j) {
            async_cp16(gBh[j] + k0, lBh[j]);
            async_cp16(gBl[j] + k0, lBl[j]);
        }
        float f[8];
        const int gk = k0 + cl * 8;
#pragma unroll
        for (int hh = 0; hh < 2; ++hh) {
            int g4 = gk + hh * 4;
            float4 v = (g4 + 4 <= IN_CH) ? *(const float4*)(gX + g4)
                                         : make_float4(0.f, 0.f, 0.f, 0.f);
            f[hh * 4 + 0] = v.x; f[hh * 4 + 1] = v.y;
            f[hh * 4 + 2] = v.z; f[hh * 4 + 3] = v.w;
        }
        bf8_t h8, l8;
#pragma unroll
        for (int j = 0; j < 8; ++j) {
            unsigned short h = f2bf(f[j]);
            h8[j] = (short)h;
            l8[j] = (short)f2bf(f[j] - bf2f(h));
        }
        *(bf8_t*)&sAh[ar * 32 + cpa * 8] = h8;
        *(bf8_t*)&sAl[ar * 32 + cpa * 8] = l8;
        __syncthreads();

        bf8_t ah[4], al[4];
#pragma unroll
        for (int mt = 0; mt < 4; ++mt) {
            ah[mt] = *(const bf8_t*)&sAh[(mt * 16 + l16) * 32 + rsw];
            al[mt] = *(const bf8_t*)&sAl[(mt * 16 + l16) * 32 + rsw];
        }
#pragma unroll
        for (int nt = 0; nt < 4; ++nt) {
            bf8_t bh = *(const bf8_t*)&sBh[(n0 + nt * 16 + l16) * 32 + rsw];
            bf8_t bl = *(const bf8_t*)&sBl[(n0 + nt * 16 + l16) * 32 + rsw];
#pragma unroll
            for (int mt = 0; mt < 4; ++mt) {
                acc[mt][nt] = __builtin_amdgcn_mfma_f32_16x16x32_bf16(ah[mt], bh, acc[mt][nt], 0, 0, 0);
                acc[mt][nt] = __builtin_amdgcn_mfma_f32_16x16x32_bf16(al[mt], bh, acc[mt][nt], 0, 0, 0);
                acc[mt][nt] = __builtin_amdgcn_mfma_f32_16x16x32_bf16(ah[mt], bl, acc[mt][nt], 0, 0, 0);
            }
        }
        __syncthreads();
    }

    const bool left = (n0 < 128);
    if (left) {
        int ncol[4];
#pragma unroll
        for (int nt = 0; nt < 4; ++nt) ncol[nt] = n0 + nt * 16 + l16;
#pragma unroll
        for (int mt = 0; mt < 4; ++mt)
#pragma unroll
            for (int r = 0; r < 4; ++r) {
                long row = m0 + mt * 16 + quad * 4 + r;
                if (row < M) {
#pragma unroll
                    for (int nt = 0; nt < 4; ++nt)
                        C0[row * 128 + ncol[nt]] = f2bf(acc[mt][nt][r]);
                }
            }
    } else {
        float badd[4];
        int   ncol[4];
#pragma unroll
        for (int nt = 0; nt < 4; ++nt) {
            int ng = n0 + nt * 16 + l16 - 128;
            ncol[nt] = ng;
            badd[nt] = bias[ng];
        }
#pragma unroll
        for (int mt = 0; mt < 4; ++mt)
#pragma unroll
            for (int r = 0; r < 4; ++r) {
                long row = m0 + mt * 16 + quad * 4 + r;
                if (row < M) {
#pragma unroll
                    for (int nt = 0; nt < 4; ++nt)
                        C1[row * 128 + ncol[nt]] = acc[mt][nt][r] + badd[nt];
                }
            }
    }
}

// ---------------------------------------------------------------------------
// CSR gather (bf16 Pl) + BN-stat tail.
// 32 lanes/node (4 ch = ushort4 8B per lane), 8 nodes/block, 8+4 unroll.
// ---------------------------------------------------------------------------
__global__ __launch_bounds__(256) void gather_agg(const unsigned short* __restrict__ Pl,
                                                  const int* __restrict__ row_start,
                                                  const int* __restrict__ csr_src,
                                                  const float* __restrict__ invdeg,
                                                  float* __restrict__ out,
                                                  float* __restrict__ rep) {
    int slot = threadIdx.x >> 5;
    int lane = threadIdx.x & 31;
    int node = blockIdx.x * 8 + slot;          // grid exact: 6250*8 = 50000
    int beg = row_start[node];
    int end = row_start[node + 1];
    const unsigned short* base = Pl + lane * 4;
    float sx = 0.f, sy = 0.f, sz = 0.f, sw = 0.f;
    int j = beg;
    for (; j + 8 <= end; j += 8) {
        int idx[8];
#pragma unroll
        for (int u = 0; u < 8; ++u) idx[u] = csr_src[j + u];
        ushort4 v[8];
#pragma unroll
        for (int u = 0; u < 8; ++u) v[u] = *(const ushort4*)(base + (long)idx[u] * HID);
#pragma unroll
        for (int u = 0; u < 8; ++u) {
            sx += bf2f(v[u].x); sy += bf2f(v[u].y);
            sz += bf2f(v[u].z); sw += bf2f(v[u].w);
        }
    }
    if (j + 4 <= end) {
        int idx[4];
#pragma unroll
        for (int u = 0; u < 4; ++u) idx[u] = csr_src[j + u];
        ushort4 v[4];
#pragma unroll
        for (int u = 0; u < 4; ++u) v[u] = *(const ushort4*)(base + (long)idx[u] * HID);
#pragma unroll
        for (int u = 0; u < 4; ++u) {
            sx += bf2f(v[u].x); sy += bf2f(v[u].y);
            sz += bf2f(v[u].z); sw += bf2f(v[u].w);
        }
        j += 4;
    }
    for (; j < end; ++j) {
        int i0 = csr_src[j];
        ushort4 v0 = *(const ushort4*)(base + (long)i0 * HID);
        sx += bf2f(v0.x); sy += bf2f(v0.y); sz += bf2f(v0.z); sw += bf2f(v0.w);
    }
    float w = invdeg[node];
    float* o = out + (long)node * HID + lane * 4;
    float4 cur = *(float4*)o;
    cur.x += sx * w;
    cur.y += sy * w;
    cur.z += sz * w;
    cur.w += sw * w;
    *(float4*)o = cur;

    // ---- BN stats tail: reduce 8 slots -> 256 atomics into rep slice ----
    __shared__ float red[8][HID];
    float* repb = rep + (blockIdx.x & (NREP - 1)) * 256;
    *(float4*)&red[slot][lane * 4] = make_float4(cur.x, cur.y, cur.z, cur.w);
    __syncthreads();
    if (threadIdx.x < HID) {
        float tsum = 0.f;
#pragma unroll
        for (int s = 0; s < 8; ++s) tsum += red[s][threadIdx.x];
        atomicAdd(&repb[threadIdx.x], tsum);
    }
    __syncthreads();
    *(float4*)&red[slot][lane * 4] = make_float4(cur.x * cur.x, cur.y * cur.y,
                                                 cur.z * cur.z, cur.w * cur.w);
    __syncthreads();
    if (threadIdx.x < HID) {
        float tsum = 0.f;
#pragma unroll
        for (int s = 0; s < 8; ++s) tsum += red[s][threadIdx.x];
        atomicAdd(&repb[HID + threadIdx.x], tsum);
    }
}

// ---------------------------------------------------------------------------
// BN apply(+ReLU): preamble reduces NREP replicated stat slices.
// ---------------------------------------------------------------------------
__global__ __launch_bounds__(256) void bn_apply_relu(float* __restrict__ h,
                                                     const float* __restrict__ rep,
                                                     const float* __restrict__ gamma,
                                                     const float* __restrict__ beta,
                                                     unsigned short* __restrict__ Hhi,
                                                     unsigned short* __restrict__ Hlo) {
    __shared__ float S[256];
    __shared__ float SC[256];
    int t = threadIdx.x;
    float a = 0.f;
#pragma unroll
    for (int r = 0; r < NREP; ++r) a += rep[r * 256 + t];
    S[t] = a;
    __syncthreads();
    if (t < HID) {
        const float invn = 1.0f / (float)N_NODES;
        float mu  = S[t] * invn;
        float var = S[HID + t] * invn - mu * mu;
        float sc  = gamma[t] * rsqrtf(var + BN_EPS);
        SC[t]       = sc;
        SC[HID + t] = beta[t] - mu * sc;
    }
    __syncthreads();

    long i = (long)blockIdx.x * 256 + t;
    if (i >= (long)N_NODES * 32) return;
    int c4 = (int)(i & 31) * 4;
    float4 sc = *(const float4*)&SC[c4];
    float4 sh = *(const float4*)&SC[HID + c4];
    float4 v  = *(float4*)&h[i * 4];
    v.x = fmaxf(v.x * sc.x + sh.x, 0.f);
    v.y = fmaxf(v.y * sc.y + sh.y, 0.f);
    v.z = fmaxf(v.z * sc.z + sh.z, 0.f);
    v.w = fmaxf(v.w * sc.w + sh.w, 0.f);
    if (Hhi) {
        ushort4 hh, ll;
        hh.x = f2bf(v.x); ll.x = f2bf(v.x - bf2f(hh.x));
        hh.y = f2bf(v.y); ll.y = f2bf(v.y - bf2f(hh.y));
        hh.z = f2bf(v.z); ll.z = f2bf(v.z - bf2f(hh.z));
        hh.w = f2bf(v.w); ll.w = f2bf(v.w - bf2f(hh.w));
        *(ushort4*)&Hhi[i * 4] = hh;
        *(ushort4*)&Hlo[i * 4] = ll;
    } else {
        *(float4*)&h[i * 4] = v;
    }
}

// ---------------------------------------------------------------------------
// fused mean-pool + head: one block/graph, 1024 thr = 8 row-walkers x 128 ch,
// 4-deep unroll per walker for MLP. out = [logits(128x2) | hg(128x128)]
// ---------------------------------------------------------------------------
__global__ __launch_bounds__(1024) void poolhead_kernel(const float* __restrict__ h,
                                                        const int* __restrict__ batch,
                                                        const float* __restrict__ Wc,
                                                        const float* __restrict__ bc,
                                                        float* __restrict__ out) {
    int g = blockIdx.x;
    int t = threadIdx.x;
    int c = t & 127;
    int half = t >> 7;                 // 0..7
    __shared__ int lo_sh, hi_sh;
    if (t == 0) {
        int lo = 0, hi = N_NODES;
        while (lo < hi) { int m = (lo + hi) >> 1; if (batch[m] < g) lo = m + 1; else hi = m; }
        lo_sh = lo;
        int lo2 = lo, hi2 = N_NODES;
        while (lo2 < hi2) { int m = (lo2 + hi2) >> 1; if (batch[m] < g + 1) lo2 = m + 1; else hi2 = m; }
        hi_sh = lo2;
    }
    __syncthreads();
    int lo = lo_sh, hi = hi_sh;
    float a0 = 0.f, a1 = 0.f, a2 = 0.f, a3 = 0.f;
    int r = lo + half;
    for (; r + 24 < hi; r += 32) {     // 4 independent loads in flight
        a0 += h[(long)(r +  0) * HID + c];
        a1 += h[(long)(r +  8) * HID + c];
        a2 += h[(long)(r + 16) * HID + c];
        a3 += h[(long)(r + 24) * HID + c];
    }
    for (; r < hi; r += 8) a0 += h[(long)r * HID + c];
    __shared__ float red[8][HID];
    red[half][c] = (a0 + a1) + (a2 + a3);
    __syncthreads();
    __shared__ float r0[HID], r1[HID];
    if (t < HID) {
        float inv = 1.0f / fmaxf((float)(hi - lo), 1.0f);
        float v = 0.f;
#pragma unroll
        for (int s = 0; s < 8; ++s) v += red[s][t];
        v *= inv;
        out[N_GRAPHS * N_CLASSES + g * HID + t] = v;   // hg
        r0[t] = v * Wc[t * 2 + 0];
        r1[t] = v * Wc[t * 2 + 1];
    }
    __syncthreads();
    if (t < 2) {
        const float* rr = t ? r1 : r0;
        float sum = bc[t];
        for (int i = 0; i < HID; ++i) sum += rr[i];
        out[g * 2 + t] = sum;
    }
}

// ---------------------------------------------------------------------------
// launch
// ---------------------------------------------------------------------------
extern "C" void kernel_launch(void* const* d_in, const int* in_sizes, int n_in,
                              void* d_out, int out_size, void* d_ws, size_t ws_size,
                              hipStream_t stream) {
    const float* x     = (const float*)d_in[0];
    const int*   ei    = (const int*)d_in[1];
    const int*   batch = (const int*)d_in[2];
    const float* W1l = (const float*)d_in[3];
    const float* W1r = (const float*)d_in[4];
    const float* b1  = (const float*)d_in[5];
    const float* g1  = (const float*)d_in[6];
    const float* be1 = (const float*)d_in[7];
    const float* W2l = (const float*)d_in[8];
    const float* W2r = (const float*)d_in[9];
    const float* b2  = (const float*)d_in[10];
    const float* g2  = (const float*)d_in[11];
    const float* be2 = (const float*)d_in[12];
    const float* W3l = (const float*)d_in[13];
    const float* W3r = (const float*)d_in[14];
    const float* b3  = (const float*)d_in[15];
    const float* g3  = (const float*)d_in[16];
    const float* be3 = (const float*)d_in[17];
    const float* Wc  = (const float*)d_in[18];
    const float* bc  = (const float*)d_in[19];

    const int* src = ei;
    const int* dst = ei + N_EDGES;

    float* ws = (float*)d_ws;
    const long FEAT = (long)N_NODES * HID;
    unsigned short* Pl16 = (unsigned short*)ws;      // FEAT ushorts (12.8MB)
    float* buf1 = ws + FEAT;                         // layer 1&3 pre/h (fp32)
    float* buf2 = ws + 2 * FEAT;                     // layer 2 pre/h (fp32)
    int*   ideg      = (int*)(ws + 3 * FEAT);        // 50000
    int*   cursor    = ideg + N_NODES;               // 50000
    int*   bsum      = cursor + N_NODES;             // 128
    int*   bflag     = bsum + 128;                   // 128
    int*   row_start = bflag + 128;                  // 50001 (pad 50004)
    int*   csr_src   = row_start + N_NODES + 4;      // 600000
    float* invdeg    = (float*)(csr_src + N_EDGES);  // 50000
    float* reps      = invdeg + N_NODES;             // 3*32*256 = 24576
    unsigned short* B1h = (unsigned short*)(reps + 3 * NREP * 256);  // 256*320
    unsigned short* B1l = B1h + 256 * KP1;
    unsigned short* B2h = B1l + 256 * KP1;                           // 256*128
    unsigned short* B2l = B2h + 256 * HID;
    unsigned short* B3h = B2l + 256 * HID;
    unsigned short* B3l = B3h + 256 * HID;
    unsigned short* Hhi = B3l + 256 * HID;                           // 50000*128
    unsigned short* Hlo = Hhi + FEAT;

    float* outp = (float*)d_out;

    const int gemm_grid   = (N_NODES + 63) / 64;     // 782
    const int gather_grid = N_NODES / 8;             // 6250 exact
    const int apply_grid  = (int)(((long)N_NODES * 32 + 255) / 256);
    const dim3 prepw_grid((256 * KP1 + 255) / 256, 3);

    // --- zero scratch (2 memsets) ---
    hipMemsetAsync(ideg, 0, (2 * N_NODES + 256) * sizeof(int), stream);
    hipMemsetAsync(reps, 0, 3 * NREP * 256 * sizeof(float), stream);

    // --- CSR build ---
    deg_kernel<<<(N_EDGES + 255) / 256, 256, 0, stream>>>(dst, ideg);
    scan_fused<<<NB, 256, 0, stream>>>(ideg, row_start, invdeg, bsum, bflag);
    fill_kernel<<<(N_EDGES + 255) / 256, 256, 0, stream>>>(src, dst, row_start, cursor, csr_src);

    // --- weight prep ---
    prep_w_all<<<prepw_grid, 256, 0, stream>>>(W1l, W1r, W2l, W2r, W3l, W3r,
                                               B1h, B1l, B2h, B2l, B3h, B3l);

    // ---------------- layer 1 (A = x fp32, split in-kernel) ----------------
    gemm_mfma_x<<<gemm_grid, 256, 0, stream>>>(x, N_NODES, B1h, B1l, b1, Pl16, buf1);
    gather_agg<<<gather_grid, 256, 0, stream>>>(Pl16, row_start, csr_src, invdeg, buf1, reps);
    bn_apply_relu<<<apply_grid, 256, 0, stream>>>(buf1, reps, g1, be1, Hhi, Hlo);

    // ---------------- layer 2 (A = h1 split, Kp=128) ----------------
    gemm_mfma<<<gemm_grid, 256, 0, stream>>>(Hhi, Hlo, N_NODES, HID, B2h, B2l, b2, Pl16, buf2);
    gather_agg<<<gather_grid, 256, 0, stream>>>(Pl16, row_start, csr_src, invdeg, buf2, reps + NREP * 256);
    bn_apply_relu<<<apply_grid, 256, 0, stream>>>(buf2, reps + NREP * 256, g2, be2, Hhi, Hlo);

    // ---------------- layer 3 (A = h2 split, Kp=128) ----------------
    gemm_mfma<<<gemm_grid, 256, 0, stream>>>(Hhi, Hlo, N_NODES, HID, B3h, B3l, b3, Pl16, buf1);
    gather_agg<<<gather_grid, 256, 0, stream>>>(Pl16, row_start, csr_src, invdeg, buf1, reps + 2 * NREP * 256);
    bn_apply_relu<<<apply_grid, 256, 0, stream>>>(buf1, reps + 2 * NREP * 256, g3, be3, nullptr, nullptr);

    // ---------------- fused pool + head ----------------
    poolhead_kernel<<<N_GRAPHS, 1024, 0, stream>>>(buf1, batch, Wc, bc, outp);
}

// Round 13
// 399.211 us; speedup vs baseline: 1.9802x; 1.1113x over previous
//
#include <hip/hip_runtime.h>

#define N_NODES   50000
#define N_EDGES   600000
#define IN_CH     300
#define HID       128
#define N_CLASSES 2
#define N_GRAPHS  128
#define BN_EPS    1e-5f

#define NB ((N_NODES + 511) / 512)   // scan blocks = 98
#define KP1 320
#define NREP 32                      // replicated BN-stat accumulators
#define DEGB ((N_EDGES + 255) / 256) // 2344

typedef __attribute__((ext_vector_type(8))) short bf8_t;   // 8 bf16 (4 VGPRs)
typedef __attribute__((ext_vector_type(4))) float f4_t;    // MFMA acc

// bf16 round-to-nearest-even helpers
__device__ __forceinline__ unsigned short f2bf(float x) {
    union { float f; unsigned u; } q; q.f = x;
    unsigned r = q.u + 0x7fffu + ((q.u >> 16) & 1u);
    return (unsigned short)(r >> 16);
}
__device__ __forceinline__ float bf2f(unsigned short h) {
    union { float f; unsigned u; } q; q.u = ((unsigned)h) << 16; return q.f;
}

// async global->LDS 16B copy: LDS dest = wave-uniform base + lane*16
__device__ __forceinline__ void async_cp16(const void* g, void* l) {
    __builtin_amdgcn_global_load_lds(
        (const __attribute__((address_space(1))) unsigned int*)g,
        (__attribute__((address_space(3))) unsigned int*)l, 16, 0, 0);
}

// ---------------------------------------------------------------------------
// combined: degree count (blocks 0..DEGB-1) + weight prep (blocks DEGB..)
// ---------------------------------------------------------------------------
__global__ __launch_bounds__(256) void deg_prepw(const int* __restrict__ dst,
                                                 int* __restrict__ ideg,
                                                 const float* __restrict__ W1l,
                                                 const float* __restrict__ W1r,
                                                 const float* __restrict__ W2l,
                                                 const float* __restrict__ W2r,
                                                 const float* __restrict__ W3l,
                                                 const float* __restrict__ W3r,
                                                 unsigned short* __restrict__ B1h,
                                                 unsigned short* __restrict__ B1l,
                                                 unsigned short* __restrict__ B2h,
                                                 unsigned short* __restrict__ B2l,
                                                 unsigned short* __restrict__ B3h,
                                                 unsigned short* __restrict__ B3l) {
    int b = blockIdx.x;
    if (b < DEGB) {
        int e = b * 256 + threadIdx.x;
        if (e < N_EDGES) atomicAdd(&ideg[dst[e]], 1);
        return;
    }
    int pb = b - DEGB;
    int layer, base;
    if (pb < 320)      { layer = 0; base = pb; }
    else if (pb < 448) { layer = 1; base = pb - 320; }
    else               { layer = 2; base = pb - 448; }
    int Kp = (layer == 0) ? KP1 : HID;
    int K  = (layer == 0) ? IN_CH : HID;
    const float* Wl = (layer == 0) ? W1l : ((layer == 1) ? W2l : W3l);
    const float* Wr = (layer == 0) ? W1r : ((layer == 1) ? W2r : W3r);
    unsigned short* Bh = (layer == 0) ? B1h : ((layer == 1) ? B2h : B3h);
    unsigned short* Bl = (layer == 0) ? B1l : ((layer == 1) ? B2l : B3l);
    int idx = base * 256 + threadIdx.x;     // grid sized exactly: 256*Kp/256 blocks
    int n = idx / Kp;
    int k = idx - n * Kp;
    float v = 0.f;
    if (k < K) v = (n < 128) ? Wl[k * 128 + n] : Wr[k * 128 + (n - 128)];
    unsigned short h = f2bf(v);
    unsigned short l = f2bf(v - bf2f(h));
    Bh[idx] = h;
    Bl[idx] = l;
}

// ---------------------------------------------------------------------------
// single-dispatch exclusive scan (decoupled lookback) + invdeg
// ---------------------------------------------------------------------------
__global__ __launch_bounds__(256) void scan_fused(const int* __restrict__ ideg,
                                                  int* __restrict__ row_start,
                                                  float* __restrict__ invdeg,
                                                  int* __restrict__ bsum,
                                                  int* __restrict__ bflag) {
    int b = blockIdx.x, t = threadIdx.x;
    int lane = t & 63, wv = t >> 6;
    int i0 = b * 512 + t * 2;
    int v0 = 0, v1 = 0;
    if (i0 < N_NODES) {
        int2 v = *(const int2*)&ideg[i0];
        v0 = v.x; v1 = v.y;
    }
    int tot = v0 + v1;
    int s = tot;                              // inclusive wave scan
#pragma unroll
    for (int d = 1; d < 64; d <<= 1) {
        int u = __shfl_up(s, d);
        if (lane >= d) s += u;
    }
    __shared__ int ws[4];
    if (lane == 63) ws[wv] = s;
    __syncthreads();
    int btot = ws[0] + ws[1] + ws[2] + ws[3];
    if (t == 0) {                             // publish early
        atomicExch(&bsum[b], btot);
        __threadfence();
        atomicExch(&bflag[b], 1);
    }
    int part = 0;
    if (t < b) {
        while (atomicAdd(&bflag[t], 0) == 0) {}
        part = atomicAdd(&bsum[t], 0);
    }
#pragma unroll
    for (int d = 1; d < 64; d <<= 1) part += __shfl_down(part, d);
    __shared__ int ps[4];
    if (lane == 0) ps[wv] = part;
    __syncthreads();
    int boff = ps[0] + ps[1] + ps[2] + ps[3];
    int woff = 0;
    for (int w = 0; w < wv; ++w) woff += ws[w];
    int base = boff + woff + (s - tot);       // exclusive prefix for i0
    if (i0 < N_NODES) {
        row_start[i0]     = base;
        row_start[i0 + 1] = base + v0;
        invdeg[i0]     = 1.0f / fmaxf((float)v0, 1.0f);
        invdeg[i0 + 1] = 1.0f / fmaxf((float)v1, 1.0f);
    }
    if (t == 0 && b == NB - 1) row_start[N_NODES] = boff + btot;
}

__global__ __launch_bounds__(256) void fill_kernel(const int* __restrict__ src,
                                                   const int* __restrict__ dst,
                                                   const int* __restrict__ row_start,
                                                   int* __restrict__ cursor,
                                                   int* __restrict__ csr_src) {
    int e = blockIdx.x * 256 + threadIdx.x;
    if (e >= N_EDGES) return;
    int d = dst[e];
    int pos = row_start[d] + atomicAdd(&cursor[d], 1);
    csr_src[pos] = src[e];
}

// ---------------------------------------------------------------------------
// layer-1 GEMM: A = x (fp32, stride 300), Dekker-split in staging.
//   C0(bf16) = x@W1l , C1(fp32) = x@W1r + bias
// block 64(M) x 256(N), 4 waves; XOR bank swizzle (R9-verified).
// ---------------------------------------------------------------------------
__global__ __launch_bounds__(256) void gemm_mfma_x(const float* __restrict__ X,
                                                   int M,
                                                   const unsigned short* __restrict__ Bhi,
                                                   const unsigned short* __restrict__ Blo,
                                                   const float* __restrict__ bias,
                                                   unsigned short* __restrict__ C0,
                                                   float* __restrict__ C1) {
    __shared__ __align__(16) unsigned short sAh[64 * 32];
    __shared__ __align__(16) unsigned short sAl[64 * 32];
    __shared__ __align__(16) unsigned short sBh[256 * 32];
    __shared__ __align__(16) unsigned short sBl[256 * 32];

    const int tid  = threadIdx.x;
    const int lane = tid & 63;
    const int wave = tid >> 6;
    const int l16  = lane & 15;
    const int quad = lane >> 4;
    const long m0  = (long)blockIdx.x * 64;
    const int  n0  = wave * 64;

    f4_t acc[4][4];
#pragma unroll
    for (int mt = 0; mt < 4; ++mt)
#pragma unroll
        for (int nt = 0; nt < 4; ++nt) acc[mt][nt] = (f4_t){0.f, 0.f, 0.f, 0.f};

    const int ar  = tid >> 2;
    const int cl  = tid & 3;
    const int cpa = cl ^ ((ar >> 1) & 3);      // physical chunk (swizzle)
    long agr = m0 + ar;
    if (agr >= M) agr = M - 1;
    const float* gX = X + agr * IN_CH;

    const int cg = ((lane & 3) ^ ((lane >> 3) & 3)) * 8;
    const unsigned short* gBh[4];
    const unsigned short* gBl[4];
    unsigned short* lBh[4];
    unsigned short* lBl[4];
#pragma unroll
    for (int j = 0; j < 4; ++j) {
        long br = wave * 64 + j * 16 + (lane >> 2);
        gBh[j] = Bhi + br * KP1 + cg;
        gBl[j] = Blo + br * KP1 + cg;
        lBh[j] = &sBh[wave * 2048 + j * 512];
        lBl[j] = &sBl[wave * 2048 + j * 512];
    }
    const int rsw = (quad ^ ((l16 >> 1) & 3)) * 8;

    for (int k0 = 0; k0 < KP1; k0 += 32) {
#pragma unroll
        for (int j = 0; j < 4; ++j) {
            async_cp16(gBh[j] + k0, lBh[j]);
            async_cp16(gBl[j] + k0, lBl[j]);
        }
        float f[8];
        const int gk = k0 + cl * 8;
#pragma unroll
        for (int hh = 0; hh < 2; ++hh) {
            int g4 = gk + hh * 4;
            float4 v = (g4 + 4 <= IN_CH) ? *(const float4*)(gX + g4)
                                         : make_float4(0.f, 0.f, 0.f, 0.f);
            f[hh * 4 + 0] = v.x; f[hh * 4 + 1] = v.y;
            f[hh * 4 + 2] = v.z; f[hh * 4 + 3] = v.w;
        }
        bf8_t h8, l8;
#pragma unroll
        for (int j = 0; j < 8; ++j) {
            unsigned short h = f2bf(f[j]);
            h8[j] = (short)h;
            l8[j] = (short)f2bf(f[j] - bf2f(h));
        }
        *(bf8_t*)&sAh[ar * 32 + cpa * 8] = h8;
        *(bf8_t*)&sAl[ar * 32 + cpa * 8] = l8;
        __syncthreads();

        bf8_t ah[4], al[4];
#pragma unroll
        for (int mt = 0; mt < 4; ++mt) {
            ah[mt] = *(const bf8_t*)&sAh[(mt * 16 + l16) * 32 + rsw];
            al[mt] = *(const bf8_t*)&sAl[(mt * 16 + l16) * 32 + rsw];
        }
#pragma unroll
        for (int nt = 0; nt < 4; ++nt) {
            bf8_t bh = *(const bf8_t*)&sBh[(n0 + nt * 16 + l16) * 32 + rsw];
            bf8_t bl = *(const bf8_t*)&sBl[(n0 + nt * 16 + l16) * 32 + rsw];
#pragma unroll
            for (int mt = 0; mt < 4; ++mt) {
                acc[mt][nt] = __builtin_amdgcn_mfma_f32_16x16x32_bf16(ah[mt], bh, acc[mt][nt], 0, 0, 0);
                acc[mt][nt] = __builtin_amdgcn_mfma_f32_16x16x32_bf16(al[mt], bh, acc[mt][nt], 0, 0, 0);
                acc[mt][nt] = __builtin_amdgcn_mfma_f32_16x16x32_bf16(ah[mt], bl, acc[mt][nt], 0, 0, 0);
            }
        }
        __syncthreads();
    }

    const bool left = (n0 < 128);
    if (left) {
        int ncol[4];
#pragma unroll
        for (int nt = 0; nt < 4; ++nt) ncol[nt] = n0 + nt * 16 + l16;
#pragma unroll
        for (int mt = 0; mt < 4; ++mt)
#pragma unroll
            for (int r = 0; r < 4; ++r) {
                long row = m0 + mt * 16 + quad * 4 + r;
                if (row < M) {
#pragma unroll
                    for (int nt = 0; nt < 4; ++nt)
                        C0[row * 128 + ncol[nt]] = f2bf(acc[mt][nt][r]);
                }
            }
    } else {
        float badd[4];
        int   ncol[4];
#pragma unroll
        for (int nt = 0; nt < 4; ++nt) {
            int ng = n0 + nt * 16 + l16 - 128;
            ncol[nt] = ng;
            badd[nt] = bias[ng];
        }
#pragma unroll
        for (int mt = 0; mt < 4; ++mt)
#pragma unroll
            for (int r = 0; r < 4; ++r) {
                long row = m0 + mt * 16 + quad * 4 + r;
                if (row < M) {
#pragma unroll
                    for (int nt = 0; nt < 4; ++nt)
                        C1[row * 128 + ncol[nt]] = acc[mt][nt][r] + badd[nt];
                }
            }
    }
}

// ---------------------------------------------------------------------------
// layers 2/3 GEMM with FUSED BatchNorm+ReLU on the A operand:
//   A = BN_relu(Hpre) computed in staging (stats from replicated reps),
//   C0(bf16) = A@Wl , C1(fp32) = A@Wr + bias.   Kp = 128 exact.
// ---------------------------------------------------------------------------
__global__ __launch_bounds__(256) void gemm_mfma_h(const float* __restrict__ Hpre,
                                                   int M,
                                                   const float* __restrict__ rep,
                                                   const float* __restrict__ gamma,
                                                   const float* __restrict__ beta,
                                                   const unsigned short* __restrict__ Bhi,
                                                   const unsigned short* __restrict__ Blo,
                                                   const float* __restrict__ bias,
                                                   unsigned short* __restrict__ C0,
                                                   float* __restrict__ C1) {
    __shared__ __align__(16) unsigned short sAh[64 * 32];
    __shared__ __align__(16) unsigned short sAl[64 * 32];
    __shared__ __align__(16) unsigned short sBh[256 * 32];
    __shared__ __align__(16) unsigned short sBl[256 * 32];
    __shared__ float S[256];
    __shared__ float sSC[256];   // [scale 128 | shift 128]

    const int tid  = threadIdx.x;
    const int lane = tid & 63;
    const int wave = tid >> 6;
    const int l16  = lane & 15;
    const int quad = lane >> 4;
    const long m0  = (long)blockIdx.x * 64;
    const int  n0  = wave * 64;

    // ---- BN scale/shift preamble ----
    {
        float a = 0.f;
#pragma unroll
        for (int r = 0; r < NREP; ++r) a += rep[r * 256 + tid];
        S[tid] = a;
        __syncthreads();
        if (tid < HID) {
            const float invn = 1.0f / (float)N_NODES;
            float mu  = S[tid] * invn;
            float var = S[HID + tid] * invn - mu * mu;
            float sc  = gamma[tid] * rsqrtf(var + BN_EPS);
            sSC[tid]       = sc;
            sSC[HID + tid] = beta[tid] - mu * sc;
        }
        __syncthreads();
    }

    f4_t acc[4][4];
#pragma unroll
    for (int mt = 0; mt < 4; ++mt)
#pragma unroll
        for (int nt = 0; nt < 4; ++nt) acc[mt][nt] = (f4_t){0.f, 0.f, 0.f, 0.f};

    const int ar  = tid >> 2;
    const int cl  = tid & 3;
    const int cpa = cl ^ ((ar >> 1) & 3);
    long agr = m0 + ar;
    if (agr >= M) agr = M - 1;
    const float* gH = Hpre + agr * HID;

    const int cg = ((lane & 3) ^ ((lane >> 3) & 3)) * 8;
    const unsigned short* gBh[4];
    const unsigned short* gBl[4];
    unsigned short* lBh[4];
    unsigned short* lBl[4];
#pragma unroll
    for (int j = 0; j < 4; ++j) {
        long br = wave * 64 + j * 16 + (lane >> 2);
        gBh[j] = Bhi + br * HID + cg;
        gBl[j] = Blo + br * HID + cg;
        lBh[j] = &sBh[wave * 2048 + j * 512];
        lBl[j] = &sBl[wave * 2048 + j * 512];
    }
    const int rsw = (quad ^ ((l16 >> 1) & 3)) * 8;

#pragma unroll
    for (int k0 = 0; k0 < HID; k0 += 32) {
#pragma unroll
        for (int j = 0; j < 4; ++j) {
            async_cp16(gBh[j] + k0, lBh[j]);
            async_cp16(gBl[j] + k0, lBl[j]);
        }
        const int gk = k0 + cl * 8;
        float4 v0 = *(const float4*)(gH + gk);
        float4 v1 = *(const float4*)(gH + gk + 4);
        float4 s0 = *(const float4*)&sSC[gk];
        float4 s1 = *(const float4*)&sSC[gk + 4];
        float4 t0 = *(const float4*)&sSC[HID + gk];
        float4 t1 = *(const float4*)&sSC[HID + gk + 4];
        float f[8];
        f[0] = fmaxf(v0.x * s0.x + t0.x, 0.f);
        f[1] = fmaxf(v0.y * s0.y + t0.y, 0.f);
        f[2] = fmaxf(v0.z * s0.z + t0.z, 0.f);
        f[3] = fmaxf(v0.w * s0.w + t0.w, 0.f);
        f[4] = fmaxf(v1.x * s1.x + t1.x, 0.f);
        f[5] = fmaxf(v1.y * s1.y + t1.y, 0.f);
        f[6] = fmaxf(v1.z * s1.z + t1.z, 0.f);
        f[7] = fmaxf(v1.w * s1.w + t1.w, 0.f);
        bf8_t h8, l8;
#pragma unroll
        for (int j = 0; j < 8; ++j) {
            unsigned short h = f2bf(f[j]);
            h8[j] = (short)h;
            l8[j] = (short)f2bf(f[j] - bf2f(h));
        }
        *(bf8_t*)&sAh[ar * 32 + cpa * 8] = h8;
        *(bf8_t*)&sAl[ar * 32 + cpa * 8] = l8;
        __syncthreads();

        bf8_t ah[4], al[4];
#pragma unroll
        for (int mt = 0; mt < 4; ++mt) {
            ah[mt] = *(const bf8_t*)&sAh[(mt * 16 + l16) * 32 + rsw];
            al[mt] = *(const bf8_t*)&sAl[(mt * 16 + l16) * 32 + rsw];
        }
#pragma unroll
        for (int nt = 0; nt < 4; ++nt) {
            bf8_t bh = *(const bf8_t*)&sBh[(n0 + nt * 16 + l16) * 32 + rsw];
            bf8_t bl = *(const bf8_t*)&sBl[(n0 + nt * 16 + l16) * 32 + rsw];
#pragma unroll
            for (int mt = 0; mt < 4; ++mt) {
                acc[mt][nt] = __builtin_amdgcn_mfma_f32_16x16x32_bf16(ah[mt], bh, acc[mt][nt], 0, 0, 0);
                acc[mt][nt] = __builtin_amdgcn_mfma_f32_16x16x32_bf16(al[mt], bh, acc[mt][nt], 0, 0, 0);
                acc[mt][nt] = __builtin_amdgcn_mfma_f32_16x16x32_bf16(ah[mt], bl, acc[mt][nt], 0, 0, 0);
            }
        }
        __syncthreads();
    }

    const bool left = (n0 < 128);
    if (left) {
        int ncol[4];
#pragma unroll
        for (int nt = 0; nt < 4; ++nt) ncol[nt] = n0 + nt * 16 + l16;
#pragma unroll
        for (int mt = 0; mt < 4; ++mt)
#pragma unroll
            for (int r = 0; r < 4; ++r) {
                long row = m0 + mt * 16 + quad * 4 + r;
                if (row < M) {
#pragma unroll
                    for (int nt = 0; nt < 4; ++nt)
                        C0[row * 128 + ncol[nt]] = f2bf(acc[mt][nt][r]);
                }
            }
    } else {
        float badd[4];
        int   ncol[4];
#pragma unroll
        for (int nt = 0; nt < 4; ++nt) {
            int ng = n0 + nt * 16 + l16 - 128;
            ncol[nt] = ng;
            badd[nt] = bias[ng];
        }
#pragma unroll
        for (int mt = 0; mt < 4; ++mt)
#pragma unroll
            for (int r = 0; r < 4; ++r) {
                long row = m0 + mt * 16 + quad * 4 + r;
                if (row < M) {
#pragma unroll
                    for (int nt = 0; nt < 4; ++nt)
                        C1[row * 128 + ncol[nt]] = acc[mt][nt][r] + badd[nt];
                }
            }
    }
}

// ---------------------------------------------------------------------------
// CSR gather (bf16 Pl) + BN-stat tail (replicated accumulators).
// 32 lanes/node, 8 nodes/block, 8+4 edge unroll.
// ---------------------------------------------------------------------------
__global__ __launch_bounds__(256) void gather_agg(const unsigned short* __restrict__ Pl,
                                                  const int* __restrict__ row_start,
                                                  const int* __restrict__ csr_src,
                                                  const float* __restrict__ invdeg,
                                                  float* __restrict__ out,
                                                  float* __restrict__ rep) {
    int slot = threadIdx.x >> 5;
    int lane = threadIdx.x & 31;
    int node = blockIdx.x * 8 + slot;          // grid exact: 6250*8 = 50000
    int beg = row_start[node];
    int end = row_start[node + 1];
    const unsigned short* base = Pl + lane * 4;
    float sx = 0.f, sy = 0.f, sz = 0.f, sw = 0.f;
    int j = beg;
    for (; j + 8 <= end; j += 8) {
        int idx[8];
#pragma unroll
        for (int u = 0; u < 8; ++u) idx[u] = csr_src[j + u];
        ushort4 v[8];
#pragma unroll
        for (int u = 0; u < 8; ++u) v[u] = *(const ushort4*)(base + (long)idx[u] * HID);
#pragma unroll
        for (int u = 0; u < 8; ++u) {
            sx += bf2f(v[u].x); sy += bf2f(v[u].y);
            sz += bf2f(v[u].z); sw += bf2f(v[u].w);
        }
    }
    if (j + 4 <= end) {
        int idx[4];
#pragma unroll
        for (int u = 0; u < 4; ++u) idx[u] = csr_src[j + u];
        ushort4 v[4];
#pragma unroll
        for (int u = 0; u < 4; ++u) v[u] = *(const ushort4*)(base + (long)idx[u] * HID);
#pragma unroll
        for (int u = 0; u < 4; ++u) {
            sx += bf2f(v[u].x); sy += bf2f(v[u].y);
            sz += bf2f(v[u].z); sw += bf2f(v[u].w);
        }
        j += 4;
    }
    for (; j < end; ++j) {
        int i0 = csr_src[j];
        ushort4 v0 = *(const ushort4*)(base + (long)i0 * HID);
        sx += bf2f(v0.x); sy += bf2f(v0.y); sz += bf2f(v0.z); sw += bf2f(v0.w);
    }
    float w = invdeg[node];
    float* o = out + (long)node * HID + lane * 4;
    float4 cur = *(float4*)o;
    cur.x += sx * w;
    cur.y += sy * w;
    cur.z += sz * w;
    cur.w += sw * w;
    *(float4*)o = cur;

    // ---- BN stats tail ----
    __shared__ float red[8][HID];
    float* repb = rep + (blockIdx.x & (NREP - 1)) * 256;
    *(float4*)&red[slot][lane * 4] = make_float4(cur.x, cur.y, cur.z, cur.w);
    __syncthreads();
    if (threadIdx.x < HID) {
        float tsum = 0.f;
#pragma unroll
        for (int s = 0; s < 8; ++s) tsum += red[s][threadIdx.x];
        atomicAdd(&repb[threadIdx.x], tsum);
    }
    __syncthreads();
    *(float4*)&red[slot][lane * 4] = make_float4(cur.x * cur.x, cur.y * cur.y,
                                                 cur.z * cur.z, cur.w * cur.w);
    __syncthreads();
    if (threadIdx.x < HID) {
        float tsum = 0.f;
#pragma unroll
        for (int s = 0; s < 8; ++s) tsum += red[s][threadIdx.x];
        atomicAdd(&repb[HID + threadIdx.x], tsum);
    }
}

// ---------------------------------------------------------------------------
// fused BN+ReLU + mean-pool + head: one block/graph, 1024 thr.
// out = [logits(128x2) | hg(128x128)]
// ---------------------------------------------------------------------------
__global__ __launch_bounds__(1024) void poolhead_bn(const float* __restrict__ h,
                                                    const int* __restrict__ batch,
                                                    const float* __restrict__ rep,
                                                    const float* __restrict__ gamma,
                                                    const float* __restrict__ beta,
                                                    const float* __restrict__ Wc,
                                                    const float* __restrict__ bc,
                                                    float* __restrict__ out) {
    __shared__ float S[256];
    __shared__ float SC[256];
    int g = blockIdx.x;
    int t = threadIdx.x;
    int c = t & 127;
    int half = t >> 7;                 // 0..7
    if (t < 256) {
        float a = 0.f;
#pragma unroll
        for (int r = 0; r < NREP; ++r) a += rep[r * 256 + t];
        S[t] = a;
    }
    __shared__ int lo_sh, hi_sh;
    if (t == 0) {
        int lo = 0, hi = N_NODES;
        while (lo < hi) { int m = (lo + hi) >> 1; if (batch[m] < g) lo = m + 1; else hi = m; }
        lo_sh = lo;
        int lo2 = lo, hi2 = N_NODES;
        while (lo2 < hi2) { int m = (lo2 + hi2) >> 1; if (batch[m] < g + 1) lo2 = m + 1; else hi2 = m; }
        hi_sh = lo2;
    }
    __syncthreads();
    if (t < HID) {
        const float invn = 1.0f / (float)N_NODES;
        float mu  = S[t] * invn;
        float var = S[HID + t] * invn - mu * mu;
        float sc  = gamma[t] * rsqrtf(var + BN_EPS);
        SC[t]       = sc;
        SC[HID + t] = beta[t] - mu * sc;
    }
    __syncthreads();
    float bsc = SC[c], bsh = SC[HID + c];
    int lo = lo_sh, hi = hi_sh;
    float a0 = 0.f, a1 = 0.f, a2 = 0.f, a3 = 0.f;
    int r = lo + half;
    for (; r + 24 < hi; r += 32) {     // 4 independent loads in flight
        a0 += fmaxf(h[(long)(r +  0) * HID + c] * bsc + bsh, 0.f);
        a1 += fmaxf(h[(long)(r +  8) * HID + c] * bsc + bsh, 0.f);
        a2 += fmaxf(h[(long)(r + 16) * HID + c] * bsc + bsh, 0.f);
        a3 += fmaxf(h[(long)(r + 24) * HID + c] * bsc + bsh, 0.f);
    }
    for (; r < hi; r += 8) a0 += fmaxf(h[(long)r * HID + c] * bsc + bsh, 0.f);
    __shared__ float red[8][HID];
    red[half][c] = (a0 + a1) + (a2 + a3);
    __syncthreads();
    __shared__ float r0[HID], r1[HID];
    if (t < HID) {
        float inv = 1.0f / fmaxf((float)(hi - lo), 1.0f);
        float v = 0.f;
#pragma unroll
        for (int s = 0; s < 8; ++s) v += red[s][t];
        v *= inv;
        out[N_GRAPHS * N_CLASSES + g * HID + t] = v;   // hg
        r0[t] = v * Wc[t * 2 + 0];
        r1[t] = v * Wc[t * 2 + 1];
    }
    __syncthreads();
    if (t < 2) {
        const float* rr = t ? r1 : r0;
        float sum = bc[t];
        for (int i = 0; i < HID; ++i) sum += rr[i];
        out[g * 2 + t] = sum;
    }
}

// ---------------------------------------------------------------------------
// launch
// ---------------------------------------------------------------------------
extern "C" void kernel_launch(void* const* d_in, const int* in_sizes, int n_in,
                              void* d_out, int out_size, void* d_ws, size_t ws_size,
                              hipStream_t stream) {
    const float* x     = (const float*)d_in[0];
    const int*   ei    = (const int*)d_in[1];
    const int*   batch = (const int*)d_in[2];
    const float* W1l = (const float*)d_in[3];
    const float* W1r = (const float*)d_in[4];
    const float* b1  = (const float*)d_in[5];
    const float* g1  = (const float*)d_in[6];
    const float* be1 = (const float*)d_in[7];
    const float* W2l = (const float*)d_in[8];
    const float* W2r = (const float*)d_in[9];
    const float* b2  = (const float*)d_in[10];
    const float* g2  = (const float*)d_in[11];
    const float* be2 = (const float*)d_in[12];
    const float* W3l = (const float*)d_in[13];
    const float* W3r = (const float*)d_in[14];
    const float* b3  = (const float*)d_in[15];
    const float* g3  = (const float*)d_in[16];
    const float* be3 = (const float*)d_in[17];
    const float* Wc  = (const float*)d_in[18];
    const float* bc  = (const float*)d_in[19];

    const int* src = ei;
    const int* dst = ei + N_EDGES;

    float* ws = (float*)d_ws;
    const long FEAT = (long)N_NODES * HID;
    unsigned short* Pl16 = (unsigned short*)ws;      // FEAT ushorts
    float* buf1 = ws + FEAT;                         // layer 1&3 pre-BN h (fp32)
    float* buf2 = ws + 2 * FEAT;                     // layer 2 pre-BN h (fp32)
    int*   ideg      = (int*)(ws + 3 * FEAT);        // 50000
    int*   cursor    = ideg + N_NODES;               // 50000
    int*   bsum      = cursor + N_NODES;             // 128
    int*   bflag     = bsum + 128;                   // 128
    int*   row_start = bflag + 128;                  // 50001 (pad 50004)
    int*   csr_src   = row_start + N_NODES + 4;      // 600000
    float* invdeg    = (float*)(csr_src + N_EDGES);  // 50000
    float* reps      = invdeg + N_NODES;             // 3*32*256 = 24576
    unsigned short* B1h = (unsigned short*)(reps + 3 * NREP * 256);  // 256*320
    unsigned short* B1l = B1h + 256 * KP1;
    unsigned short* B2h = B1l + 256 * KP1;                           // 256*128
    unsigned short* B2l = B2h + 256 * HID;
    unsigned short* B3h = B2l + 256 * HID;
    unsigned short* B3l = B3h + 256 * HID;

    float* outp = (float*)d_out;

    const int gemm_grid   = (N_NODES + 63) / 64;     // 782
    const int gather_grid = N_NODES / 8;             // 6250 exact
    const int dp_grid     = DEGB + 320 + 128 + 128;  // 2920

    // --- zero scratch (2 memsets) ---
    hipMemsetAsync(ideg, 0, (2 * N_NODES + 256) * sizeof(int), stream);
    hipMemsetAsync(reps, 0, 3 * NREP * 256 * sizeof(float), stream);

    // --- degree + weight prep (merged), then scan, fill ---
    deg_prepw<<<dp_grid, 256, 0, stream>>>(dst, ideg, W1l, W1r, W2l, W2r, W3l, W3r,
                                           B1h, B1l, B2h, B2l, B3h, B3l);
    scan_fused<<<NB, 256, 0, stream>>>(ideg, row_start, invdeg, bsum, bflag);
    fill_kernel<<<(N_EDGES + 255) / 256, 256, 0, stream>>>(src, dst, row_start, cursor, csr_src);

    // ---------------- layer 1 ----------------
    gemm_mfma_x<<<gemm_grid, 256, 0, stream>>>(x, N_NODES, B1h, B1l, b1, Pl16, buf1);
    gather_agg<<<gather_grid, 256, 0, stream>>>(Pl16, row_start, csr_src, invdeg, buf1, reps);

    // ---------------- layer 2 (BN1 fused into A-staging) ----------------
    gemm_mfma_h<<<gemm_grid, 256, 0, stream>>>(buf1, N_NODES, reps, g1, be1,
                                               B2h, B2l, b2, Pl16, buf2);
    gather_agg<<<gather_grid, 256, 0, stream>>>(Pl16, row_start, csr_src, invdeg, buf2, reps + NREP * 256);

    // ---------------- layer 3 (BN2 fused into A-staging) ----------------
    gemm_mfma_h<<<gemm_grid, 256, 0, stream>>>(buf2, N_NODES, reps + NREP * 256, g2, be2,
                                               B3h, B3l, b3, Pl16, buf1);
    gather_agg<<<gather_grid, 256, 0, stream>>>(Pl16, row_start, csr_src, invdeg, buf1, reps + 2 * NREP * 256);

    // ---------------- fused BN3 + pool + head ----------------
    poolhead_bn<<<N_GRAPHS, 1024, 0, stream>>>(buf1, batch, reps + 2 * NREP * 256,
                                               g3, be3, Wc, bc, outp);
}